// Round 7
// baseline (367.128 us; speedup 1.0000x reference)
//
#include <hip/hip_runtime.h>
#include <cmath>

#define IN_CH 128
#define NBUCK 128
#define LNMAX 392   // ceil(50048/128); node local id = node>>7
// Cacheable (L1/L2) relaxed probe: ws is monotone-decreasing so stale reads are
// stale-HIGH => safe (can only cause a rejected proposal, never a wrong skip).
#define PLW(p) __hip_atomic_load((p), __ATOMIC_RELAXED, __HIP_MEMORY_SCOPE_WORKGROUP)

typedef unsigned long long ull;
typedef ull  ull2 __attribute__((ext_vector_type(2)));
typedef float f4  __attribute__((ext_vector_type(4)));

// Monotone descending key: smaller key == higher norm; ties -> smaller edge idx
// (matches stable argsort of -norm). All keys distinct. Low 32 bits = edge idx.
__device__ __forceinline__ ull make_key(float norm, int e) {
    unsigned int b = __float_as_uint(norm);
    unsigned int asc = (b & 0x80000000u) ? ~b : (b | 0x80000000u); // monotone-increasing map
    unsigned int desc = ~asc;
    return (((ull)desc) << 32) | (unsigned int)e;
}

// Edge norm, identical arithmetic to the old norm_key kernel (and ref):
// ev=(float)exp((double)(s-m)); nv=ev/d+0.5f; 0 for non-positive; raw score
// when the source node has no positive edge. u MUST be row[e] (= rc[e].x).
__device__ __forceinline__ float norm_of(int e, int u, const float* __restrict__ score,
                                         const unsigned int* __restrict__ node_max,
                                         const double* __restrict__ denom) {
    unsigned int mb = node_max[u];
    float s = score[e];
    if (mb != 0u) {
        if (s > 0.0f) {
            float m = __uint_as_float(mb);
            float ev = (float)exp((double)(s - m));
            float d = (float)denom[u];
            return ev / d + 0.5f;           // exact f32 div + add, same as ref
        }
        return 0.0f;
    }
    return s;
}

// One wave per node: p[n] = dot(x[n], w_src), q[n] = dot(x[n], w_dst), double accum.
// Per-node state init + counter zeroing folded in.
__global__ void proj_kernel(const float* __restrict__ x, const float* __restrict__ w_src,
                            const float* __restrict__ w_dst, float* __restrict__ p,
                            float* __restrict__ q,
                            ull* __restrict__ wsuit,
                            int* __restrict__ cluster, int* __restrict__ partner,
                            float* __restrict__ s_rep, int* __restrict__ bump,
                            int* __restrict__ btail, int N) {
    int gtid = blockIdx.x * blockDim.x + threadIdx.x;
    if (gtid == 0) *bump = 0;
    if (gtid < NBUCK) btail[gtid] = 0;
    if (gtid < N) {
        wsuit[gtid]    = ~0ULL;
        cluster[gtid]  = gtid;
        partner[gtid]  = gtid;
        s_rep[gtid]    = 1.0f;
    }
    int wave = gtid >> 6;
    int lane = threadIdx.x & 63;
    if (wave >= N) return;
    float2 xv = ((const float2*)(x + (size_t)wave * IN_CH))[lane];
    float2 ws = ((const float2*)w_src)[lane];
    float2 wd = ((const float2*)w_dst)[lane];
    double ap = (double)xv.x * (double)ws.x + (double)xv.y * (double)ws.y;
    double aq = (double)xv.x * (double)wd.x + (double)xv.y * (double)wd.y;
    #pragma unroll
    for (int off = 32; off > 0; off >>= 1) {
        ap += __shfl_down(ap, off);
        aq += __shfl_down(aq, off);
    }
    if (lane == 0) { p[wave] = (float)ap; q[wave] = (float)aq; }
}

// Fused: edge score + rc pack + 128-bucket build. No global atomics.
// Entry (pre-slot form): e[0:19] | side[20] | (node>>7)[21:29] | self[30]
// Self-loops (u==v) get one side-0 entry with self=1: they contribute to
// node_max/denom but must NOT enter the adjacency (can't match).
__global__ void score_kernel(const int* __restrict__ row, const int* __restrict__ col,
                             const float* __restrict__ p, const float* __restrict__ q,
                             const float* __restrict__ bptr, float* __restrict__ score,
                             int2* __restrict__ rc, int* __restrict__ btail,
                             unsigned int* __restrict__ bucket, int bcap, int E) {
    __shared__ int cnt[NBUCK];
    __shared__ int gbase[NBUCK];
    int e = blockIdx.x * blockDim.x + threadIdx.x;
    if (threadIdx.x < NBUCK) cnt[threadIdx.x] = 0;
    __syncthreads();
    bool inb = e < E;
    int u = 0, v = 0, l1 = -1, l2 = -1, h1 = 0, h2 = 0;
    unsigned int selfbit = 0;
    if (inb) {
        u = row[e]; v = col[e];
        rc[e] = make_int2(u, v);
        float s = p[u] + q[v] + bptr[0];
        score[e] = s;
        selfbit = (u == v) ? (1u << 30) : 0u;
        h1 = u & (NBUCK - 1); l1 = atomicAdd(&cnt[h1], 1);   // side-0 entry (always)
        if (u != v) {
            h2 = v & (NBUCK - 1); l2 = atomicAdd(&cnt[h2], 1);
        }
    }
    __syncthreads();
    if (threadIdx.x < NBUCK) gbase[threadIdx.x] = atomicAdd(&btail[threadIdx.x], cnt[threadIdx.x]);
    __syncthreads();
    if (l1 >= 0) bucket[(size_t)h1 * bcap + gbase[h1] + l1] =
        (unsigned int)e | ((unsigned int)(u >> 7) << 21) | selfbit;
    if (l2 >= 0) bucket[(size_t)h2 * bcap + gbase[h2] + l2] =
        (unsigned int)e | (1u << 20) | ((unsigned int)(v >> 7) << 21);
}

// One WG (512 thr) per bucket; bucket b owns nodes n with (n&127)==b (<=391).
// Pass 1: node_max via LDS atomicMax over side-0 entries (incl. self).
// Pass 2: denom via LDS f64 atomicAdd; slot assignment via LDS hist; entries
// rewritten to slot form e[0:19]|side[20]|slot[21:31]; self -> 0xFFFFFFFF.
// Pass 3: per-bucket LDS prefix-scan of 64B-padded degrees -> ONE global
// atomicAdd(bump, total) per bucket; seg[node] = base + exclusive prefix.
__global__ void slot_kernel(unsigned int* __restrict__ bucket, const int* __restrict__ btail,
                            int bcap, const float* __restrict__ score,
                            unsigned int* __restrict__ node_max, double* __restrict__ denom,
                            int* __restrict__ bump, int2* __restrict__ seg, int N) {
    __shared__ int hist[LNMAX];
    __shared__ unsigned int maxv[LNMAX];
    __shared__ double dden[LNMAX];
    __shared__ int scan[512];
    __shared__ int basesh;
    int b = blockIdx.x;
    int t = threadIdx.x;
    for (int i = t; i < LNMAX; i += blockDim.x) {
        hist[i] = 0; maxv[i] = 0u; dden[i] = 0.0;
    }
    __syncthreads();
    int n = btail[b];
    unsigned int* bk = bucket + (size_t)b * bcap;
    // pass 1: per-node max of positive source-side scores
    for (int i = t; i < n; i += blockDim.x) {
        unsigned int ent = bk[i];
        if (!(ent & (1u << 20))) {                 // side 0 (incl. self)
            int e = (int)(ent & 0xfffffu);
            float s = score[e];
            if (s > 0.0f) {
                int ln = (int)((ent >> 21) & 0x1ffu);
                atomicMax(&maxv[ln], __float_as_uint(s));
            }
        }
    }
    __syncthreads();
    // pass 2: denom accumulate + slot assign + rewrite
    for (int i = t; i < n; i += blockDim.x) {
        unsigned int ent = bk[i];
        int ln = (int)((ent >> 21) & 0x1ffu);
        if (!(ent & (1u << 20))) {                 // side 0: denom contribution
            unsigned int mb = maxv[ln];
            int e = (int)(ent & 0xfffffu);
            float s = score[e];
            if (mb != 0u && s > 0.0f) {
                float m = __uint_as_float(mb);
                float ev = (float)exp((double)(s - m));
                atomicAdd(&dden[ln], (double)ev);
            }
        }
        if (ent & (1u << 30)) {
            bk[i] = 0xFFFFFFFFu;                   // self: no adjacency slot
        } else {
            int slot = atomicAdd(&hist[ln], 1);
            bk[i] = (ent & 0x1fffffu) | ((unsigned int)slot << 21);
        }
    }
    __syncthreads();
    // pass 3: seg allocation via LDS inclusive scan (blockDim == 512 >= LNMAX)
    int node = (t << 7) | b;
    int d  = (t < LNMAX && node < N) ? hist[t] : 0;
    int pd = (d + 3) & ~3;                         // 64B-padded segment size
    scan[t] = pd;
    __syncthreads();
    #pragma unroll
    for (int off = 1; off < 512; off <<= 1) {
        int add = (t >= off) ? scan[t - off] : 0;
        __syncthreads();
        scan[t] += add;
        __syncthreads();
    }
    if (t == 511) basesh = atomicAdd(bump, scan[511]);   // ONE global RMW/bucket
    __syncthreads();
    if (t < LNMAX && node < N) {
        int lo = basesh + scan[t] - pd;
        seg[node]      = make_int2(lo, lo + d);
        node_max[node] = maxv[t];
        denom[node]    = dden[t];
    }
}

// Phase B: XCD-pinned CSR scatter, atomic-free (pos = seg.lo + slot).
// Computes the key INLINE (replaces the deleted norm_key kernel + keyn buffer
// + its 3.2M random 8B gathers). Key arithmetic bit-identical: both sides of
// an edge compute the same (score, node_max[u], denom[u]) -> same key.
// bucket b -> XCD b&7 (node&7 preserved): all writers of a node's line-
// aligned segment share one XCD; adj lines stay dirty-resident in that XCD's
// L2 for the suitor kernel that follows.
__global__ void csr_scatter_kernel(const unsigned int* __restrict__ bucket,
                                   const int* __restrict__ btail, int bcap,
                                   const float* __restrict__ score,
                                   const unsigned int* __restrict__ node_max,
                                   const double* __restrict__ denom,
                                   const int2* __restrict__ rc,
                                   const int2* __restrict__ seg,
                                   ull2* __restrict__ adj, int bpx) {
    int xcd = blockIdx.x & 7;
    int sub = blockIdx.x >> 3;
    for (int bb = 0; bb < NBUCK / 8; ++bb) {
        int b = xcd + (bb << 3);
        int n = btail[b];
        const unsigned int* bk = bucket + (size_t)b * bcap;
        for (int i = sub * blockDim.x + threadIdx.x; i < n; i += bpx * blockDim.x) {
            unsigned int ent = bk[i];
            if (ent == 0xFFFFFFFFu) continue;      // self-loop sentinel
            int e    = (int)(ent & 0xfffffu);
            int side = (int)((ent >> 20) & 1u);
            int slot = (int)(ent >> 21);
            int2 pr = rc[e];
            int dst = side ? pr.y : pr.x;
            int nb  = side ? pr.x : pr.y;
            ull2 w;
            w.x = make_key(norm_of(e, pr.x, score, node_max, denom), e);
            w.y = (ull)nb;
            adj[seg[dst].x + slot] = w;
        }
    }
}

// ---- Suitor matching (Manne-Bisseling), 32-lane-group-per-node. R3 probe
// scheme (best measured): cacheable probes of ws directly (stale-high => safe
// filter), progress guaranteed by excl (a rejection proves ws[bv] <= bk;
// proposal keys strictly increase between takeovers).
// XCD-ALIGNED group mapping: node = ((b>>3)*8 + lg)*8 + (b&7) so node%8 ==
// blockIdx%8 == XCD of the scatter writer -> initial seg+adj scan hits the
// local L2. R7 FIX: grid must be a whole number of block-OCTETS (8 blocks
// cover 64 nodes); R6's grid had 2 leftover blocks, leaving 12 nodes with no
// proposing group -> wrong matching. Launcher now rounds blocks up to
// ceil(N/64)*8; the grp>=N guard discards overflow groups.
__global__ void suitor_kernel(const int2* __restrict__ seg,
                              const ull2* __restrict__ adj,
                              const int2* __restrict__ rc,
                              ull* __restrict__ ws, int N) {
    int lg   = threadIdx.x >> 5;            // local group 0..7
    int b    = blockIdx.x;
    int grp  = ((((b >> 3) << 3) + lg) << 3) | (b & 7);   // node; node%8==b%8
    int lane = threadIdx.x & 31;
    if (grp >= N) return;
    int cur = grp;
    int2 lohi;
    ull excl = 0ULL;          // keys <= excl proven infeasible for cur (monotone)
    ull lk = ~0ULL;           // lane-local best candidate key
    int lv = -1;              // its neighbor
    bool reload = true;
    for (int guard = 0; guard < 1000000; ++guard) {
        if (reload) {
            lohi = seg[cur];
            excl = 0ULL;
            lk = ~0ULL; lv = -1;
            for (int i = lohi.x + lane; i < lohi.y; i += 32) {
                ull2 ent = adj[i];              // coalesced 16B, XCD-local L2
                ull k = ent.x;
                if (k < lk) {
                    int v = (int)ent.y;
                    if (k < PLW(&ws[v])) { lk = k; lv = v; }  // cached probe
                }
            }
            reload = false;
        } else if (lk != ~0ULL && lk <= excl) {
            // this lane owned the rejected key: recompute from its entries
            lk = ~0ULL; lv = -1;
            for (int i = lohi.x + lane; i < lohi.y; i += 32) {
                ull2 ent = adj[i];              // L1/L2-hot re-read, 1-2 entries
                ull k = ent.x;
                if (k > excl && k < lk) {
                    int v = (int)ent.y;
                    if (k < PLW(&ws[v])) { lk = k; lv = v; }
                }
            }
        }
        // group-wide butterfly min-reduce with payload (width 32)
        ull bk = lk; int bv = lv;
        #pragma unroll
        for (int off = 16; off > 0; off >>= 1) {
            ull ok = __shfl_xor(bk, off, 32);
            int ov = __shfl_xor(bv, off, 32);
            if (ok < bk) { bk = ok; bv = ov; }
        }
        if (bk == ~0ULL) break;             // no feasible proposal: cur stays unmatched
        ull old;
        if (lane == 0) old = atomicMin(&ws[bv], bk);
        old = __shfl(old, 0, 32);
        if (old <= bk) {
            excl = bk;                      // proven infeasible; next proposal key > bk
            continue;
        }
        // accepted; take over the displaced proposer (atomicMin hands each
        // displaced value to exactly one group)
        if (old == ~0ULL) break;
        int e = (int)(old & 0xffffffffu);
        int2 pr = rc[e];                    // same address across group -> broadcast
        cur = pr.x ^ pr.y ^ bv;             // displaced proposer = other endpoint of e
        reload = true;
    }
}

// Node-centric extract: each node's standing proposal names its edge; matched
// iff mutual (ws[a]==ws[b]==k). The a-side thread writes (once per pair).
// norm recomputed inline for the matched edges (norm buffer deleted).
__global__ void extract_kernel(const int2* __restrict__ rc,
                               const float* __restrict__ score,
                               const unsigned int* __restrict__ node_max,
                               const double* __restrict__ denom,
                               const ull* __restrict__ ws,
                               int* __restrict__ cluster, int* __restrict__ partner,
                               float* __restrict__ s_rep, int N) {
    int w = blockIdx.x * blockDim.x + threadIdx.x;
    if (w >= N) return;
    ull k = ws[w];
    if (k == ~0ULL) return;
    int e = (int)(k & 0xffffffffu);
    int2 pr = rc[e];                        // w is an endpoint of e
    int a = pr.x, b = pr.y;
    if (w != a) return;                     // b-side duplicate: skip
    if (ws[b] == k) {                       // mutual => matched (ws[a]==k by construction)
        cluster[b] = a;                     // b merged into rep a (ref: cluster[c_s]=r_s)
        partner[a] = b;
        s_rep[a]   = norm_of(e, a, score, node_max, denom);
    }
}

// Fused epilogue: blocks [0, NB1) do new_x/cluster/is_rep; blocks [NB1, ..) do
// edges. nt ONLY on the fully-coalesced f4 newx stream.
__global__ void out_kernel(const float* __restrict__ x, const int* __restrict__ cluster,
                           const int* __restrict__ partner, const float* __restrict__ s_rep,
                           const int* __restrict__ row, const int* __restrict__ col,
                           const float* __restrict__ w,
                           float* __restrict__ out_newx, float* __restrict__ out_cluster,
                           float* __restrict__ out_isrep, float* __restrict__ out_nrow,
                           float* __restrict__ out_ncol, float* __restrict__ out_valid,
                           float* __restrict__ out_w, int N, int E, int NB1) {
    if ((int)blockIdx.x < NB1) {
        int t = blockIdx.x * blockDim.x + threadIdx.x;
        if (t >= N * (IN_CH / 4)) return;
        int n = t >> 5;            // IN_CH/4 == 32 float4 per node
        int c = (t & 31) * 4;
        int cl = cluster[n];
        if ((t & 31) == 0) {
            out_cluster[n] = (float)cl;
            out_isrep[n]   = (cl == n) ? 1.0f : 0.0f;
        }
        f4 o;
        int v = partner[n];
        if (cl != n) {
            o = (f4)0.0f;                                     // merged-away node row
        } else if (v != n) {
            float s = s_rep[n];
            f4 xu = *(const f4*)(x + (size_t)n * IN_CH + c);
            f4 xv = *(const f4*)(x + (size_t)v * IN_CH + c);
            o = (xu + xv) * s + xv;
        } else {
            o = *(const f4*)(x + (size_t)n * IN_CH + c);      // untouched node
        }
        __builtin_nontemporal_store(o, (f4*)out_newx + t);
    } else {
        int e = (blockIdx.x - NB1) * blockDim.x + threadIdx.x;
        if (e >= E) return;
        int nr = cluster[row[e]];
        int nc = cluster[col[e]];
        out_nrow[e]  = (float)nr;
        out_ncol[e]  = (float)nc;
        out_valid[e] = (nr != nc) ? 1.0f : 0.0f;
        out_w[e]     = w[e];
    }
}

extern "C" void kernel_launch(void* const* d_in, const int* in_sizes, int n_in_args,
                              void* d_out, int out_size, void* d_ws, size_t ws_size,
                              hipStream_t stream) {
    const float* x     = (const float*)d_in[0];
    const float* w_src = (const float*)d_in[1];
    const float* w_dst = (const float*)d_in[2];
    const float* bptr  = (const float*)d_in[3];
    const int*   ei    = (const int*)d_in[4];
    const float* ew    = (const float*)d_in[5];
    const int N = in_sizes[0] / IN_CH;
    const int E = in_sizes[5];
    const int* row = ei;
    const int* col = ei + E;

    char* wsb = (char*)d_ws;
    size_t off = 0;
    auto alloc = [&](size_t bytes) -> void* {
        off = (off + 255) & ~(size_t)255;
        void* ptr = wsb + off;
        off += bytes;
        return ptr;
    };
    // 128 buckets: expected (2E)/128 = 12500 entries each, sigma ~110; big slack.
    const int bcap = E / 64 + E / 512 + 1024;
    float*        score    = (float*)alloc((size_t)E * 4);
    int2*         rc       = (int2*)alloc((size_t)E * 8);
    ull2*         adj      = (ull2*)alloc(((size_t)2 * E + 4 * N) * 16);
    unsigned int* bucket   = (unsigned int*)alloc((size_t)NBUCK * bcap * 4);
    unsigned int* node_max = (unsigned int*)alloc((size_t)N * 4);
    double*       denom    = (double*)alloc((size_t)N * 8);
    ull*          wsuit    = (ull*)alloc((size_t)N * 8);
    int2*         seg      = (int2*)alloc((size_t)N * 8);
    int*          cluster  = (int*)alloc((size_t)N * 4);
    int*          partner  = (int*)alloc((size_t)N * 4);
    float*        s_rep    = (float*)alloc((size_t)N * 4);
    float*        pbuf     = (float*)alloc((size_t)N * 4);
    float*        qbuf     = (float*)alloc((size_t)N * 4);
    int*          bump     = (int*)alloc(64);
    int*          btail    = (int*)alloc((size_t)NBUCK * 4);

    // Output layout: new_x[N*128] | cluster[N] | is_rep[N] | new_row[E] | new_col[E] | edge_valid[E] | edge_weight[E]
    float* out       = (float*)d_out;
    float* o_newx    = out;
    float* o_cluster = out + (size_t)N * IN_CH;
    float* o_isrep   = o_cluster + N;
    float* o_nrow    = o_isrep + N;
    float* o_ncol    = o_nrow + E;
    float* o_valid   = o_ncol + E;
    float* o_w       = o_valid + E;

    const int T = 256;
    const int TS = 512;
    hipLaunchKernelGGL(proj_kernel, dim3((N * 64 + T - 1) / T), dim3(T), 0, stream,
                       x, w_src, w_dst, pbuf, qbuf,
                       wsuit, cluster, partner, s_rep, bump, btail, N);
    hipLaunchKernelGGL(score_kernel, dim3((E + TS - 1) / TS), dim3(TS), 0, stream,
                       row, col, pbuf, qbuf, bptr, score, rc,
                       btail, bucket, bcap, E);
    hipLaunchKernelGGL(slot_kernel, dim3(NBUCK), dim3(512), 0, stream,
                       bucket, btail, bcap, score, node_max, denom, bump, seg, N);
    const int bpx = 40;                     // blocks per XCD slot
    hipLaunchKernelGGL(csr_scatter_kernel, dim3(8 * bpx), dim3(T), 0, stream,
                       bucket, btail, bcap, score, node_max, denom, rc, seg, adj, bpx);
    // R7 FIX: whole octets of blocks (8 blocks <-> 64 nodes) so the XCD-aligned
    // remap covers every node exactly once.
    const int SB = ((N + 63) / 64) * 8;
    hipLaunchKernelGGL(suitor_kernel, dim3(SB), dim3(T), 0, stream,
                       seg, adj, rc, wsuit, N);
    hipLaunchKernelGGL(extract_kernel, dim3((N + T - 1) / T), dim3(T), 0, stream,
                       rc, score, node_max, denom, wsuit, cluster, partner, s_rep, N);
    const int NB1 = (N * 32 + T - 1) / T;
    const int NB2 = (E + T - 1) / T;
    hipLaunchKernelGGL(out_kernel, dim3(NB1 + NB2), dim3(T), 0, stream,
                       x, cluster, partner, s_rep, row, col, ew,
                       o_newx, o_cluster, o_isrep, o_nrow, o_ncol, o_valid, o_w, N, E, NB1);
    (void)ws_size; (void)out_size; (void)n_in_args;
}

// Round 8
// 316.409 us; speedup vs baseline: 1.1603x; 1.1603x over previous
//
#include <hip/hip_runtime.h>
#include <cmath>

#define IN_CH 128
#define NBUCK 256
#define LNMAX 196   // ceil(50048/256); node local id = node>>8
// Cacheable (L1/L2) relaxed probe: ws is monotone-decreasing so stale reads are
// stale-HIGH => safe (can only cause a rejected proposal, never a wrong skip).
#define PLW(p) __hip_atomic_load((p), __ATOMIC_RELAXED, __HIP_MEMORY_SCOPE_WORKGROUP)

typedef unsigned long long ull;
typedef ull  ull2 __attribute__((ext_vector_type(2)));
typedef float f4  __attribute__((ext_vector_type(4)));

// Monotone descending key: smaller key == higher norm; ties -> smaller edge idx
// (matches stable argsort of -norm). All keys distinct. Low 32 bits = edge idx.
__device__ __forceinline__ ull make_key(float norm, int e) {
    unsigned int b = __float_as_uint(norm);
    unsigned int asc = (b & 0x80000000u) ? ~b : (b | 0x80000000u); // monotone-increasing map
    unsigned int desc = ~asc;
    return (((ull)desc) << 32) | (unsigned int)e;
}

// One wave per node: p[n] = dot(x[n], w_src), q[n] = dot(x[n], w_dst), double accum.
// Per-node state init + counter zeroing folded in.
__global__ void proj_kernel(const float* __restrict__ x, const float* __restrict__ w_src,
                            const float* __restrict__ w_dst, float* __restrict__ p,
                            float* __restrict__ q,
                            ull* __restrict__ wsuit,
                            int* __restrict__ cluster, int* __restrict__ partner,
                            float* __restrict__ s_rep, int* __restrict__ bump,
                            int* __restrict__ btail, int N) {
    int gtid = blockIdx.x * blockDim.x + threadIdx.x;
    if (gtid == 0) *bump = 0;
    if (gtid < NBUCK) btail[gtid] = 0;
    if (gtid < N) {
        wsuit[gtid]    = ~0ULL;
        cluster[gtid]  = gtid;
        partner[gtid]  = gtid;
        s_rep[gtid]    = 1.0f;
    }
    int wave = gtid >> 6;
    int lane = threadIdx.x & 63;
    if (wave >= N) return;
    float2 xv = ((const float2*)(x + (size_t)wave * IN_CH))[lane];
    float2 ws = ((const float2*)w_src)[lane];
    float2 wd = ((const float2*)w_dst)[lane];
    double ap = (double)xv.x * (double)ws.x + (double)xv.y * (double)ws.y;
    double aq = (double)xv.x * (double)wd.x + (double)xv.y * (double)wd.y;
    #pragma unroll
    for (int off = 32; off > 0; off >>= 1) {
        ap += __shfl_down(ap, off);
        aq += __shfl_down(aq, off);
    }
    if (lane == 0) { p[wave] = (float)ap; q[wave] = (float)aq; }
}

// Fused: edge score + rc pack + 256-bucket build. No global atomics.
// Entry (pre-slot form): e[0:19] | side[20] | (node>>8)[21:28] | self[30]
// Self-loops (u==v) get one side-0 entry with self=1: they contribute to
// node_max/denom but must NOT enter the adjacency (can't match).
__global__ void score_kernel(const int* __restrict__ row, const int* __restrict__ col,
                             const float* __restrict__ p, const float* __restrict__ q,
                             const float* __restrict__ bptr, float* __restrict__ score,
                             int2* __restrict__ rc, int* __restrict__ btail,
                             unsigned int* __restrict__ bucket, int bcap, int E) {
    __shared__ int cnt[NBUCK];
    __shared__ int gbase[NBUCK];
    int e = blockIdx.x * blockDim.x + threadIdx.x;
    if (threadIdx.x < NBUCK) cnt[threadIdx.x] = 0;
    __syncthreads();
    bool inb = e < E;
    int u = 0, v = 0, l1 = -1, l2 = -1, h1 = 0, h2 = 0;
    unsigned int selfbit = 0;
    if (inb) {
        u = row[e]; v = col[e];
        rc[e] = make_int2(u, v);
        float s = p[u] + q[v] + bptr[0];
        score[e] = s;
        selfbit = (u == v) ? (1u << 30) : 0u;
        h1 = u & (NBUCK - 1); l1 = atomicAdd(&cnt[h1], 1);   // side-0 entry (always)
        if (u != v) {
            h2 = v & (NBUCK - 1); l2 = atomicAdd(&cnt[h2], 1);
        }
    }
    __syncthreads();
    if (threadIdx.x < NBUCK) gbase[threadIdx.x] = atomicAdd(&btail[threadIdx.x], cnt[threadIdx.x]);
    __syncthreads();
    if (l1 >= 0) bucket[(size_t)h1 * bcap + gbase[h1] + l1] =
        (unsigned int)e | ((unsigned int)(u >> 8) << 21) | selfbit;
    if (l2 >= 0) bucket[(size_t)h2 * bcap + gbase[h2] + l2] =
        (unsigned int)e | (1u << 20) | ((unsigned int)(v >> 8) << 21);
}

// One WG (1024 thr) per bucket; bucket b owns nodes n with (n&255)==b (<=196).
// R8: 256 buckets x 1024 threads (was 128x512) -> 4x the thread-level
// parallelism (slot was 12.5% of chip thread capacity, latency-bound on its
// random score gathers). n&255 preserves n&7, so XCD pinning is unchanged.
// Pass 1: node_max via LDS atomicMax over side-0 entries (incl. self).
// Pass 2: denom via LDS f64 atomicAdd; slot assignment via LDS hist; entries
// rewritten to slot form e[0:19]|side[20]|slot[21:31]; self -> 0xFFFFFFFF.
// Pass 3: per-bucket LDS prefix-scan of 64B-padded degrees -> ONE global
// atomicAdd(bump, total) per bucket; seg[node] = base + exclusive prefix.
__global__ void slot_kernel(unsigned int* __restrict__ bucket, const int* __restrict__ btail,
                            int bcap, const float* __restrict__ score,
                            unsigned int* __restrict__ node_max, double* __restrict__ denom,
                            int* __restrict__ bump, int2* __restrict__ seg, int N) {
    __shared__ int hist[LNMAX];
    __shared__ unsigned int maxv[LNMAX];
    __shared__ double dden[LNMAX];
    __shared__ int scan[256];
    __shared__ int basesh;
    int b = blockIdx.x;
    int t = threadIdx.x;
    for (int i = t; i < LNMAX; i += blockDim.x) {
        hist[i] = 0; maxv[i] = 0u; dden[i] = 0.0;
    }
    __syncthreads();
    int n = btail[b];
    unsigned int* bk = bucket + (size_t)b * bcap;
    // pass 1: per-node max of positive source-side scores
    for (int i = t; i < n; i += blockDim.x) {
        unsigned int ent = bk[i];
        if (!(ent & (1u << 20))) {                 // side 0 (incl. self)
            int e = (int)(ent & 0xfffffu);
            float s = score[e];
            if (s > 0.0f) {
                int ln = (int)((ent >> 21) & 0x1ffu);
                atomicMax(&maxv[ln], __float_as_uint(s));
            }
        }
    }
    __syncthreads();
    // pass 2: denom accumulate + slot assign + rewrite
    for (int i = t; i < n; i += blockDim.x) {
        unsigned int ent = bk[i];
        int ln = (int)((ent >> 21) & 0x1ffu);
        if (!(ent & (1u << 20))) {                 // side 0: denom contribution
            unsigned int mb = maxv[ln];
            int e = (int)(ent & 0xfffffu);
            float s = score[e];
            if (mb != 0u && s > 0.0f) {
                float m = __uint_as_float(mb);
                float ev = (float)exp((double)(s - m));
                atomicAdd(&dden[ln], (double)ev);
            }
        }
        if (ent & (1u << 30)) {
            bk[i] = 0xFFFFFFFFu;                   // self: no adjacency slot
        } else {
            int slot = atomicAdd(&hist[ln], 1);
            bk[i] = (ent & 0x1fffffu) | ((unsigned int)slot << 21);
        }
    }
    __syncthreads();
    // pass 3: seg allocation via LDS inclusive scan over 256 slots (>= LNMAX);
    // whole block participates in barriers, first 256 threads carry values.
    if (t < 256) {
        int node = (t << 8) | b;
        int d = (t < LNMAX && node < N) ? hist[t] : 0;
        scan[t] = (d + 3) & ~3;                    // 64B-padded segment size
    }
    __syncthreads();
    #pragma unroll
    for (int off = 1; off < 256; off <<= 1) {
        int add = (t < 256 && t >= off) ? scan[t - off] : 0;
        __syncthreads();
        if (t < 256) scan[t] += add;
        __syncthreads();
    }
    if (t == 255) basesh = atomicAdd(bump, scan[255]);   // ONE global RMW/bucket
    __syncthreads();
    if (t < LNMAX) {
        int node = (t << 8) | b;
        if (node < N) {
            int d  = hist[t];
            int pd = (d + 3) & ~3;
            int lo = basesh + scan[t] - pd;
            seg[node]      = make_int2(lo, lo + d);
            node_max[node] = maxv[t];
            denom[node]    = dden[t];
        }
    }
}

// Phase A: finalize norm (identical arithmetic to ref: ev=(float)exp((double)
// (s-m)); nv=ev/d+0.5f) + coalesced key write. Pure streaming edge kernel.
// R8: RESTORED as a separate kernel (R6/R7 inlined the key into scatter: 4
// random gathers/entry + f64 exp there cost more than this kernel saves).
__global__ void norm_key_kernel(const int* __restrict__ row, const float* __restrict__ score,
                                const unsigned int* __restrict__ node_max,
                                const double* __restrict__ denom, float* __restrict__ norm,
                                ull* __restrict__ keyn, int E) {
    int e = blockIdx.x * blockDim.x + threadIdx.x;
    if (e >= E) return;
    int u = row[e];
    unsigned int mb = node_max[u];
    float nv;
    if (mb != 0u) {
        float s = score[e];
        if (s > 0.0f) {
            float m = __uint_as_float(mb);
            float ev = (float)exp((double)(s - m));
            float d = (float)denom[u];
            nv = ev / d + 0.5f;                   // exact f32 div + add, same as ref
        } else {
            nv = 0.0f;
        }
    } else {
        nv = score[e];                            // raw score for rows with no positive edge
    }
    norm[e] = nv;
    keyn[e] = make_key(nv, e);
}

// Phase B: XCD-pinned CSR scatter, atomic-free (pos = seg.lo + slot).
// bucket b -> XCD b&7 (node&7 preserved) so all writers of a node's
// line-aligned segment share one XCD. R8: bpx 40->80 (latency-bound on its
// keyn/rc/seg gathers; double the blocks in flight).
__global__ void csr_scatter_kernel(const unsigned int* __restrict__ bucket,
                                   const int* __restrict__ btail, int bcap,
                                   const ull* __restrict__ keyn, const int2* __restrict__ rc,
                                   const int2* __restrict__ seg,
                                   ull2* __restrict__ adj, int bpx) {
    int xcd = blockIdx.x & 7;
    int sub = blockIdx.x >> 3;
    for (int bb = 0; bb < NBUCK / 8; ++bb) {
        int b = xcd + (bb << 3);
        int n = btail[b];
        const unsigned int* bk = bucket + (size_t)b * bcap;
        for (int i = sub * blockDim.x + threadIdx.x; i < n; i += bpx * blockDim.x) {
            unsigned int ent = bk[i];
            if (ent == 0xFFFFFFFFu) continue;      // self-loop sentinel
            int e    = (int)(ent & 0xfffffu);
            int side = (int)((ent >> 20) & 1u);
            int slot = (int)(ent >> 21);
            int2 pr = rc[e];
            int dst = side ? pr.y : pr.x;
            int nb  = side ? pr.x : pr.y;
            ull2 w; w.x = keyn[e]; w.y = (ull)nb;
            adj[seg[dst].x + slot] = w;
        }
    }
}

// ---- Suitor matching (Manne-Bisseling), 32-lane-group-per-node. R3 probe
// scheme (best measured): cacheable probes of ws directly (stale-high => safe
// filter), progress guaranteed by excl (a rejection proves ws[bv] <= bk;
// proposal keys strictly increase between takeovers).
// XCD-aligned group mapping (neutral but harmless); grid MUST be whole
// octets of blocks (8 blocks <-> 64 nodes): launcher uses ceil(N/64)*8.
__global__ void suitor_kernel(const int2* __restrict__ seg,
                              const ull2* __restrict__ adj,
                              const int2* __restrict__ rc,
                              ull* __restrict__ ws, int N) {
    int lg   = threadIdx.x >> 5;            // local group 0..7
    int b    = blockIdx.x;
    int grp  = ((((b >> 3) << 3) + lg) << 3) | (b & 7);   // node; node%8==b%8
    int lane = threadIdx.x & 31;
    if (grp >= N) return;
    int cur = grp;
    int2 lohi;
    ull excl = 0ULL;          // keys <= excl proven infeasible for cur (monotone)
    ull lk = ~0ULL;           // lane-local best candidate key
    int lv = -1;              // its neighbor
    bool reload = true;
    for (int guard = 0; guard < 1000000; ++guard) {
        if (reload) {
            lohi = seg[cur];
            excl = 0ULL;
            lk = ~0ULL; lv = -1;
            for (int i = lohi.x + lane; i < lohi.y; i += 32) {
                ull2 ent = adj[i];              // coalesced 16B
                ull k = ent.x;
                if (k < lk) {
                    int v = (int)ent.y;
                    if (k < PLW(&ws[v])) { lk = k; lv = v; }  // cached probe
                }
            }
            reload = false;
        } else if (lk != ~0ULL && lk <= excl) {
            // this lane owned the rejected key: recompute from its entries
            lk = ~0ULL; lv = -1;
            for (int i = lohi.x + lane; i < lohi.y; i += 32) {
                ull2 ent = adj[i];              // L1/L2-hot re-read, 1-2 entries
                ull k = ent.x;
                if (k > excl && k < lk) {
                    int v = (int)ent.y;
                    if (k < PLW(&ws[v])) { lk = k; lv = v; }
                }
            }
        }
        // group-wide butterfly min-reduce with payload (width 32)
        ull bk = lk; int bv = lv;
        #pragma unroll
        for (int off = 16; off > 0; off >>= 1) {
            ull ok = __shfl_xor(bk, off, 32);
            int ov = __shfl_xor(bv, off, 32);
            if (ok < bk) { bk = ok; bv = ov; }
        }
        if (bk == ~0ULL) break;             // no feasible proposal: cur stays unmatched
        ull old;
        if (lane == 0) old = atomicMin(&ws[bv], bk);
        old = __shfl(old, 0, 32);
        if (old <= bk) {
            excl = bk;                      // proven infeasible; next proposal key > bk
            continue;
        }
        // accepted; take over the displaced proposer (atomicMin hands each
        // displaced value to exactly one group)
        if (old == ~0ULL) break;
        int e = (int)(old & 0xffffffffu);
        int2 pr = rc[e];                    // same address across group -> broadcast
        cur = pr.x ^ pr.y ^ bv;             // displaced proposer = other endpoint of e
        reload = true;
    }
}

// Node-centric extract: each node's standing proposal names its edge; matched
// iff mutual (ws[a]==ws[b]==k). The a-side thread writes (once per pair).
__global__ void extract_kernel(const int2* __restrict__ rc, const float* __restrict__ norm,
                               const ull* __restrict__ ws,
                               int* __restrict__ cluster, int* __restrict__ partner,
                               float* __restrict__ s_rep, int N) {
    int w = blockIdx.x * blockDim.x + threadIdx.x;
    if (w >= N) return;
    ull k = ws[w];
    if (k == ~0ULL) return;
    int e = (int)(k & 0xffffffffu);
    int2 pr = rc[e];                        // w is an endpoint of e
    int a = pr.x, b = pr.y;
    if (w != a) return;                     // b-side duplicate: skip
    if (ws[b] == k) {                       // mutual => matched (ws[a]==k by construction)
        cluster[b] = a;                     // b merged into rep a (ref: cluster[c_s]=r_s)
        partner[a] = b;
        s_rep[a]   = norm[e];
    }
}

// Fused epilogue: blocks [0, NB1) do new_x/cluster/is_rep; blocks [NB1, ..) do
// edges. nt ONLY on the fully-coalesced f4 newx stream.
__global__ void out_kernel(const float* __restrict__ x, const int* __restrict__ cluster,
                           const int* __restrict__ partner, const float* __restrict__ s_rep,
                           const int* __restrict__ row, const int* __restrict__ col,
                           const float* __restrict__ w,
                           float* __restrict__ out_newx, float* __restrict__ out_cluster,
                           float* __restrict__ out_isrep, float* __restrict__ out_nrow,
                           float* __restrict__ out_ncol, float* __restrict__ out_valid,
                           float* __restrict__ out_w, int N, int E, int NB1) {
    if ((int)blockIdx.x < NB1) {
        int t = blockIdx.x * blockDim.x + threadIdx.x;
        if (t >= N * (IN_CH / 4)) return;
        int n = t >> 5;            // IN_CH/4 == 32 float4 per node
        int c = (t & 31) * 4;
        int cl = cluster[n];
        if ((t & 31) == 0) {
            out_cluster[n] = (float)cl;
            out_isrep[n]   = (cl == n) ? 1.0f : 0.0f;
        }
        f4 o;
        int v = partner[n];
        if (cl != n) {
            o = (f4)0.0f;                                     // merged-away node row
        } else if (v != n) {
            float s = s_rep[n];
            f4 xu = *(const f4*)(x + (size_t)n * IN_CH + c);
            f4 xv = *(const f4*)(x + (size_t)v * IN_CH + c);
            o = (xu + xv) * s + xv;
        } else {
            o = *(const f4*)(x + (size_t)n * IN_CH + c);      // untouched node
        }
        __builtin_nontemporal_store(o, (f4*)out_newx + t);
    } else {
        int e = (blockIdx.x - NB1) * blockDim.x + threadIdx.x;
        if (e >= E) return;
        int nr = cluster[row[e]];
        int nc = cluster[col[e]];
        out_nrow[e]  = (float)nr;
        out_ncol[e]  = (float)nc;
        out_valid[e] = (nr != nc) ? 1.0f : 0.0f;
        out_w[e]     = w[e];
    }
}

extern "C" void kernel_launch(void* const* d_in, const int* in_sizes, int n_in_args,
                              void* d_out, int out_size, void* d_ws, size_t ws_size,
                              hipStream_t stream) {
    const float* x     = (const float*)d_in[0];
    const float* w_src = (const float*)d_in[1];
    const float* w_dst = (const float*)d_in[2];
    const float* bptr  = (const float*)d_in[3];
    const int*   ei    = (const int*)d_in[4];
    const float* ew    = (const float*)d_in[5];
    const int N = in_sizes[0] / IN_CH;
    const int E = in_sizes[5];
    const int* row = ei;
    const int* col = ei + E;

    char* wsb = (char*)d_ws;
    size_t off = 0;
    auto alloc = [&](size_t bytes) -> void* {
        off = (off + 255) & ~(size_t)255;
        void* ptr = wsb + off;
        off += bytes;
        return ptr;
    };
    // 256 buckets: expected (2E)/256 = 6250 entries each, sigma ~80; big slack.
    const int bcap = E / 128 + E / 1024 + 1024;
    float*        score    = (float*)alloc((size_t)E * 4);
    float*        norm     = (float*)alloc((size_t)E * 4);
    int2*         rc       = (int2*)alloc((size_t)E * 8);
    ull*          keyn     = (ull*)alloc((size_t)E * 8);
    ull2*         adj      = (ull2*)alloc(((size_t)2 * E + 4 * N) * 16);
    unsigned int* bucket   = (unsigned int*)alloc((size_t)NBUCK * bcap * 4);
    unsigned int* node_max = (unsigned int*)alloc((size_t)N * 4);
    double*       denom    = (double*)alloc((size_t)N * 8);
    ull*          wsuit    = (ull*)alloc((size_t)N * 8);
    int2*         seg      = (int2*)alloc((size_t)N * 8);
    int*          cluster  = (int*)alloc((size_t)N * 4);
    int*          partner  = (int*)alloc((size_t)N * 4);
    float*        s_rep    = (float*)alloc((size_t)N * 4);
    float*        pbuf     = (float*)alloc((size_t)N * 4);
    float*        qbuf     = (float*)alloc((size_t)N * 4);
    int*          bump     = (int*)alloc(64);
    int*          btail    = (int*)alloc((size_t)NBUCK * 4);

    // Output layout: new_x[N*128] | cluster[N] | is_rep[N] | new_row[E] | new_col[E] | edge_valid[E] | edge_weight[E]
    float* out       = (float*)d_out;
    float* o_newx    = out;
    float* o_cluster = out + (size_t)N * IN_CH;
    float* o_isrep   = o_cluster + N;
    float* o_nrow    = o_isrep + N;
    float* o_ncol    = o_nrow + E;
    float* o_valid   = o_ncol + E;
    float* o_w       = o_valid + E;

    const int T = 256;
    const int TS = 1024;                    // score: keeps 8-entry bucket chunks at NBUCK=256
    hipLaunchKernelGGL(proj_kernel, dim3((N * 64 + T - 1) / T), dim3(T), 0, stream,
                       x, w_src, w_dst, pbuf, qbuf,
                       wsuit, cluster, partner, s_rep, bump, btail, N);
    hipLaunchKernelGGL(score_kernel, dim3((E + TS - 1) / TS), dim3(TS), 0, stream,
                       row, col, pbuf, qbuf, bptr, score, rc,
                       btail, bucket, bcap, E);
    hipLaunchKernelGGL(slot_kernel, dim3(NBUCK), dim3(1024), 0, stream,
                       bucket, btail, bcap, score, node_max, denom, bump, seg, N);
    hipLaunchKernelGGL(norm_key_kernel, dim3((E + T - 1) / T), dim3(T), 0, stream,
                       row, score, node_max, denom, norm, keyn, E);
    const int bpx = 80;                     // blocks per XCD slot (R8: 2x)
    hipLaunchKernelGGL(csr_scatter_kernel, dim3(8 * bpx), dim3(T), 0, stream,
                       bucket, btail, bcap, keyn, rc, seg, adj, bpx);
    const int SB = ((N + 63) / 64) * 8;     // whole octets: remap covers every node
    hipLaunchKernelGGL(suitor_kernel, dim3(SB), dim3(T), 0, stream,
                       seg, adj, rc, wsuit, N);
    hipLaunchKernelGGL(extract_kernel, dim3((N + T - 1) / T), dim3(T), 0, stream,
                       rc, norm, wsuit, cluster, partner, s_rep, N);
    const int NB1 = (N * 32 + T - 1) / T;
    const int NB2 = (E + T - 1) / T;
    hipLaunchKernelGGL(out_kernel, dim3(NB1 + NB2), dim3(T), 0, stream,
                       x, cluster, partner, s_rep, row, col, ew,
                       o_newx, o_cluster, o_isrep, o_nrow, o_ncol, o_valid, o_w, N, E, NB1);
    (void)ws_size; (void)out_size; (void)n_in_args;
}

// Round 9
// 295.908 us; speedup vs baseline: 1.2407x; 1.0693x over previous
//
#include <hip/hip_runtime.h>
#include <cmath>

#define IN_CH 128
#define NBUCK 256
#define LNMAX 196   // ceil(50048/256); node local id = node>>8
#define SIDE_BIT (1u << 20)
#define SELF_BIT (1u << 21)
// Cacheable (L1/L2) relaxed probe: ws is monotone-decreasing so stale reads are
// stale-HIGH => safe (can only cause a rejected proposal, never a wrong skip).
#define PLW(p) __hip_atomic_load((p), __ATOMIC_RELAXED, __HIP_MEMORY_SCOPE_WORKGROUP)

typedef unsigned long long ull;
typedef ull  ull2 __attribute__((ext_vector_type(2)));
typedef float f4  __attribute__((ext_vector_type(4)));

// Monotone descending key: smaller key == higher norm; ties -> smaller edge idx
// (matches stable argsort of -norm). All keys distinct. Low 32 bits = edge idx.
__device__ __forceinline__ ull make_key(float norm, int e) {
    unsigned int b = __float_as_uint(norm);
    unsigned int asc = (b & 0x80000000u) ? ~b : (b | 0x80000000u); // monotone-increasing map
    unsigned int desc = ~asc;
    return (((ull)desc) << 32) | (unsigned int)e;
}

// Norm from raw score s and source-node stats. IDENTICAL float ops to the old
// norm_key kernel (and ref): ev=(float)exp((double)(s-m)); nv=ev/d+0.5f;
// 0 for non-positive; raw score when source node has no positive edge.
__device__ __forceinline__ float norm_from(float s, unsigned int mb, double den) {
    if (mb != 0u) {
        if (s > 0.0f) {
            float m = __uint_as_float(mb);
            float ev = (float)exp((double)(s - m));
            float d = (float)den;
            return ev / d + 0.5f;
        }
        return 0.0f;
    }
    return s;
}

// One wave per node: p[n] = dot(x[n], w_src), q[n] = dot(x[n], w_dst), double accum.
// Per-node state init + counter zeroing folded in.
__global__ void proj_kernel(const float* __restrict__ x, const float* __restrict__ w_src,
                            const float* __restrict__ w_dst, float* __restrict__ p,
                            float* __restrict__ q,
                            ull* __restrict__ wsuit,
                            int* __restrict__ cluster, int* __restrict__ partner,
                            float* __restrict__ s_rep, int* __restrict__ bump,
                            int* __restrict__ btail, int N) {
    int gtid = blockIdx.x * blockDim.x + threadIdx.x;
    if (gtid == 0) *bump = 0;
    if (gtid < NBUCK) btail[gtid] = 0;
    if (gtid < N) {
        wsuit[gtid]    = ~0ULL;
        cluster[gtid]  = gtid;
        partner[gtid]  = gtid;
        s_rep[gtid]    = 1.0f;
    }
    int wave = gtid >> 6;
    int lane = threadIdx.x & 63;
    if (wave >= N) return;
    float2 xv = ((const float2*)(x + (size_t)wave * IN_CH))[lane];
    float2 ws = ((const float2*)w_src)[lane];
    float2 wd = ((const float2*)w_dst)[lane];
    double ap = (double)xv.x * (double)ws.x + (double)xv.y * (double)ws.y;
    double aq = (double)xv.x * (double)wd.x + (double)xv.y * (double)wd.y;
    #pragma unroll
    for (int off = 32; off > 0; off >>= 1) {
        ap += __shfl_down(ap, off);
        aq += __shfl_down(aq, off);
    }
    if (lane == 0) { p[wave] = (float)ap; q[wave] = (float)aq; }
}

// Fused: edge score + rc pack + 256-bucket build. No global atomics.
// R9: entries carry everything downstream kernels need (kills the slot score
// gathers and the scatter keyn/rc gathers):
//   bucketA[i] = { e[0:19]|side[20]|self[21],  nb[0:16]|ln[17:25] }
//   bucketS[i] = raw score float (same value for both sides of an edge)
// Self-loops (u==v): one side-0 entry with self=1 (contributes to node_max/
// denom, never enters adjacency). score/norm/keyn arrays are DELETED.
__global__ void score_kernel(const int* __restrict__ row, const int* __restrict__ col,
                             const float* __restrict__ p, const float* __restrict__ q,
                             const float* __restrict__ bptr,
                             int2* __restrict__ rc, int* __restrict__ btail,
                             uint2* __restrict__ bucketA, float* __restrict__ bucketS,
                             int bcap, int E) {
    __shared__ int cnt[NBUCK];
    __shared__ int gbase[NBUCK];
    int e = blockIdx.x * blockDim.x + threadIdx.x;
    if (threadIdx.x < NBUCK) cnt[threadIdx.x] = 0;
    __syncthreads();
    bool inb = e < E;
    int u = 0, v = 0, l1 = -1, l2 = -1, h1 = 0, h2 = 0;
    float s = 0.0f;
    if (inb) {
        u = row[e]; v = col[e];
        rc[e] = make_int2(u, v);
        s = p[u] + q[v] + bptr[0];
        h1 = u & (NBUCK - 1); l1 = atomicAdd(&cnt[h1], 1);   // side-0 entry (always)
        if (u != v) {
            h2 = v & (NBUCK - 1); l2 = atomicAdd(&cnt[h2], 1);
        }
    }
    __syncthreads();
    if (threadIdx.x < NBUCK) gbase[threadIdx.x] = atomicAdd(&btail[threadIdx.x], cnt[threadIdx.x]);
    __syncthreads();
    if (l1 >= 0) {
        size_t idx = (size_t)h1 * bcap + gbase[h1] + l1;
        unsigned int w0 = (unsigned int)e | ((u == v) ? SELF_BIT : 0u);
        bucketA[idx] = make_uint2(w0, (unsigned int)v | ((unsigned int)(u >> 8) << 17));
        bucketS[idx] = s;
    }
    if (l2 >= 0) {
        size_t idx = (size_t)h2 * bcap + gbase[h2] + l2;
        bucketA[idx] = make_uint2((unsigned int)e | SIDE_BIT,
                                  (unsigned int)u | ((unsigned int)(v >> 8) << 17));
        bucketS[idx] = s;
    }
}

// One WG (1024 thr) per bucket; bucket b owns nodes n with (n&255)==b (<=196).
// R9: score comes INLINE from bucketS (no global gathers at all).
// Pass 1: node_max via LDS atomicMax over side-0 entries (incl. self).
// Pass 2: denom via LDS f64 atomicAdd; slot assignment via LDS hist; word0
// rewritten to e[0:19]|side[20]|slot[21:31]; self -> 0xFFFFFFFF (e==0xFFFFF
// impossible since E<2^20-1). word1 (nb|ln) untouched.
// Pass 3: per-bucket LDS prefix-scan of 64B-padded degrees -> ONE global
// atomicAdd(bump, total) per bucket; seg[node] = base + exclusive prefix.
__global__ void slot_kernel(uint2* __restrict__ bucketA, const float* __restrict__ bucketS,
                            const int* __restrict__ btail, int bcap,
                            unsigned int* __restrict__ node_max, double* __restrict__ denom,
                            int* __restrict__ bump, int2* __restrict__ seg, int N) {
    __shared__ int hist[LNMAX];
    __shared__ unsigned int maxv[LNMAX];
    __shared__ double dden[LNMAX];
    __shared__ int scan[256];
    __shared__ int basesh;
    int b = blockIdx.x;
    int t = threadIdx.x;
    for (int i = t; i < LNMAX; i += blockDim.x) {
        hist[i] = 0; maxv[i] = 0u; dden[i] = 0.0;
    }
    __syncthreads();
    int n = btail[b];
    uint2* bkA = bucketA + (size_t)b * bcap;
    const float* bkS = bucketS + (size_t)b * bcap;
    // pass 1: per-node max of positive source-side scores
    for (int i = t; i < n; i += blockDim.x) {
        uint2 en = bkA[i];
        if (!(en.x & SIDE_BIT)) {                  // side 0 (incl. self)
            float s = bkS[i];
            if (s > 0.0f) {
                int ln = (int)((en.y >> 17) & 0x1ffu);
                atomicMax(&maxv[ln], __float_as_uint(s));
            }
        }
    }
    __syncthreads();
    // pass 2: denom accumulate + slot assign + rewrite
    for (int i = t; i < n; i += blockDim.x) {
        uint2 en = bkA[i];
        int ln = (int)((en.y >> 17) & 0x1ffu);
        if (!(en.x & SIDE_BIT)) {                  // side 0: denom contribution
            unsigned int mb = maxv[ln];
            float s = bkS[i];
            if (mb != 0u && s > 0.0f) {
                float m = __uint_as_float(mb);
                float ev = (float)exp((double)(s - m));
                atomicAdd(&dden[ln], (double)ev);
            }
        }
        if (en.x & SELF_BIT) {
            bkA[i].x = 0xFFFFFFFFu;                // self: no adjacency slot
        } else {
            int slot = atomicAdd(&hist[ln], 1);
            bkA[i].x = (en.x & 0x1fffffu) | ((unsigned int)slot << 21);
        }
    }
    __syncthreads();
    // pass 3: seg allocation via LDS inclusive scan over 256 slots (>= LNMAX)
    if (t < 256) {
        int node = (t << 8) | b;
        int d = (t < LNMAX && node < N) ? hist[t] : 0;
        scan[t] = (d + 3) & ~3;                    // 64B-padded segment size
    }
    __syncthreads();
    #pragma unroll
    for (int off = 1; off < 256; off <<= 1) {
        int add = (t < 256 && t >= off) ? scan[t - off] : 0;
        __syncthreads();
        if (t < 256) scan[t] += add;
        __syncthreads();
    }
    if (t == 255) basesh = atomicAdd(bump, scan[255]);   // ONE global RMW/bucket
    __syncthreads();
    if (t < LNMAX) {
        int node = (t << 8) | b;
        if (node < N) {
            int d  = hist[t];
            int pd = (d + 3) & ~3;
            int lo = basesh + scan[t] - pd;
            seg[node]      = make_int2(lo, lo + d);
            node_max[node] = maxv[t];
            denom[node]    = dden[t];
        }
    }
}

// Phase B: XCD-pinned CSR scatter, atomic-free (pos = seg.lo + slot).
// R9: key computed INLINE from entry-carried score + L2-resident node stats
// (node_max 200KB, denom 400KB, each line reused ~32x). No keyn/rc gathers.
// Both sides of an edge compute the same (s, node_max[u], denom[u]) -> same
// key; adjacency content identical to the R8 pipeline.
// bucket b -> XCD b&7 (node&7 preserved): all writers of a node's line-
// aligned segment share one XCD.
__global__ void csr_scatter_kernel(const uint2* __restrict__ bucketA,
                                   const float* __restrict__ bucketS,
                                   const int* __restrict__ btail, int bcap,
                                   const unsigned int* __restrict__ node_max,
                                   const double* __restrict__ denom,
                                   const int2* __restrict__ seg,
                                   ull2* __restrict__ adj, int bpx) {
    int xcd = blockIdx.x & 7;
    int sub = blockIdx.x >> 3;
    for (int bb = 0; bb < NBUCK / 8; ++bb) {
        int b = xcd + (bb << 3);
        int n = btail[b];
        const uint2* bkA = bucketA + (size_t)b * bcap;
        const float* bkS = bucketS + (size_t)b * bcap;
        for (int i = sub * blockDim.x + threadIdx.x; i < n; i += bpx * blockDim.x) {
            uint2 en = bkA[i];
            if (en.x == 0xFFFFFFFFu) continue;     // self-loop sentinel
            int e    = (int)(en.x & 0xfffffu);
            int side = (int)((en.x >> 20) & 1u);
            int slot = (int)(en.x >> 21);
            int nb   = (int)(en.y & 0x1ffffu);
            int ln   = (int)((en.y >> 17) & 0x1ffu);
            int dst  = (ln << 8) | b;
            int u    = side ? nb : dst;            // source (row) node of e
            float nv = norm_from(bkS[i], node_max[u], denom[u]);
            ull2 w; w.x = make_key(nv, e); w.y = (ull)nb;
            adj[seg[dst].x + slot] = w;
        }
    }
}

// ---- Suitor matching (Manne-Bisseling), 32-lane-group-per-node. R3 probe
// scheme (best measured): cacheable probes of ws directly (stale-high => safe
// filter), progress guaranteed by excl (a rejection proves ws[bv] <= bk;
// proposal keys strictly increase between takeovers).
// Grid MUST be whole octets of blocks (8 blocks <-> 64 nodes): ceil(N/64)*8.
__global__ void suitor_kernel(const int2* __restrict__ seg,
                              const ull2* __restrict__ adj,
                              const int2* __restrict__ rc,
                              ull* __restrict__ ws, int N) {
    int lg   = threadIdx.x >> 5;            // local group 0..7
    int b    = blockIdx.x;
    int grp  = ((((b >> 3) << 3) + lg) << 3) | (b & 7);   // node; node%8==b%8
    int lane = threadIdx.x & 31;
    if (grp >= N) return;
    int cur = grp;
    int2 lohi;
    ull excl = 0ULL;          // keys <= excl proven infeasible for cur (monotone)
    ull lk = ~0ULL;           // lane-local best candidate key
    int lv = -1;              // its neighbor
    bool reload = true;
    for (int guard = 0; guard < 1000000; ++guard) {
        if (reload) {
            lohi = seg[cur];
            excl = 0ULL;
            lk = ~0ULL; lv = -1;
            for (int i = lohi.x + lane; i < lohi.y; i += 32) {
                ull2 ent = adj[i];              // coalesced 16B
                ull k = ent.x;
                if (k < lk) {
                    int v = (int)ent.y;
                    if (k < PLW(&ws[v])) { lk = k; lv = v; }  // cached probe
                }
            }
            reload = false;
        } else if (lk != ~0ULL && lk <= excl) {
            // this lane owned the rejected key: recompute from its entries
            lk = ~0ULL; lv = -1;
            for (int i = lohi.x + lane; i < lohi.y; i += 32) {
                ull2 ent = adj[i];              // L1/L2-hot re-read, 1-2 entries
                ull k = ent.x;
                if (k > excl && k < lk) {
                    int v = (int)ent.y;
                    if (k < PLW(&ws[v])) { lk = k; lv = v; }
                }
            }
        }
        // group-wide butterfly min-reduce with payload (width 32)
        ull bk = lk; int bv = lv;
        #pragma unroll
        for (int off = 16; off > 0; off >>= 1) {
            ull ok = __shfl_xor(bk, off, 32);
            int ov = __shfl_xor(bv, off, 32);
            if (ok < bk) { bk = ok; bv = ov; }
        }
        if (bk == ~0ULL) break;             // no feasible proposal: cur stays unmatched
        ull old;
        if (lane == 0) old = atomicMin(&ws[bv], bk);
        old = __shfl(old, 0, 32);
        if (old <= bk) {
            excl = bk;                      // proven infeasible; next proposal key > bk
            continue;
        }
        // accepted; take over the displaced proposer (atomicMin hands each
        // displaced value to exactly one group)
        if (old == ~0ULL) break;
        int e = (int)(old & 0xffffffffu);
        int2 pr = rc[e];                    // same address across group -> broadcast
        cur = pr.x ^ pr.y ^ bv;             // displaced proposer = other endpoint of e
        reload = true;
    }
}

// Node-centric extract: each node's standing proposal names its edge; matched
// iff mutual (ws[a]==ws[b]==k). The a-side thread writes (once per pair).
// R9: s_rep recomputed inline: s = p[a]+q[b]+bias (bit-identical to
// score_kernel's expression) + L2-resident stats. norm/score arrays deleted.
__global__ void extract_kernel(const int2* __restrict__ rc,
                               const float* __restrict__ p, const float* __restrict__ q,
                               const float* __restrict__ bptr,
                               const unsigned int* __restrict__ node_max,
                               const double* __restrict__ denom,
                               const ull* __restrict__ ws,
                               int* __restrict__ cluster, int* __restrict__ partner,
                               float* __restrict__ s_rep, int N) {
    int w = blockIdx.x * blockDim.x + threadIdx.x;
    if (w >= N) return;
    ull k = ws[w];
    if (k == ~0ULL) return;
    int e = (int)(k & 0xffffffffu);
    int2 pr = rc[e];                        // w is an endpoint of e
    int a = pr.x, b = pr.y;
    if (w != a) return;                     // b-side duplicate: skip
    if (ws[b] == k) {                       // mutual => matched (ws[a]==k by construction)
        cluster[b] = a;                     // b merged into rep a (ref: cluster[c_s]=r_s)
        partner[a] = b;
        float s = p[a] + q[b] + bptr[0];    // same float ops as score_kernel
        s_rep[a] = norm_from(s, node_max[a], denom[a]);
    }
}

// Fused epilogue: blocks [0, NB1) do new_x/cluster/is_rep; blocks [NB1, ..) do
// edges. nt ONLY on the fully-coalesced f4 newx stream.
__global__ void out_kernel(const float* __restrict__ x, const int* __restrict__ cluster,
                           const int* __restrict__ partner, const float* __restrict__ s_rep,
                           const int* __restrict__ row, const int* __restrict__ col,
                           const float* __restrict__ w,
                           float* __restrict__ out_newx, float* __restrict__ out_cluster,
                           float* __restrict__ out_isrep, float* __restrict__ out_nrow,
                           float* __restrict__ out_ncol, float* __restrict__ out_valid,
                           float* __restrict__ out_w, int N, int E, int NB1) {
    if ((int)blockIdx.x < NB1) {
        int t = blockIdx.x * blockDim.x + threadIdx.x;
        if (t >= N * (IN_CH / 4)) return;
        int n = t >> 5;            // IN_CH/4 == 32 float4 per node
        int c = (t & 31) * 4;
        int cl = cluster[n];
        if ((t & 31) == 0) {
            out_cluster[n] = (float)cl;
            out_isrep[n]   = (cl == n) ? 1.0f : 0.0f;
        }
        f4 o;
        int v = partner[n];
        if (cl != n) {
            o = (f4)0.0f;                                     // merged-away node row
        } else if (v != n) {
            float s = s_rep[n];
            f4 xu = *(const f4*)(x + (size_t)n * IN_CH + c);
            f4 xv = *(const f4*)(x + (size_t)v * IN_CH + c);
            o = (xu + xv) * s + xv;
        } else {
            o = *(const f4*)(x + (size_t)n * IN_CH + c);      // untouched node
        }
        __builtin_nontemporal_store(o, (f4*)out_newx + t);
    } else {
        int e = (blockIdx.x - NB1) * blockDim.x + threadIdx.x;
        if (e >= E) return;
        int nr = cluster[row[e]];
        int nc = cluster[col[e]];
        out_nrow[e]  = (float)nr;
        out_ncol[e]  = (float)nc;
        out_valid[e] = (nr != nc) ? 1.0f : 0.0f;
        out_w[e]     = w[e];
    }
}

extern "C" void kernel_launch(void* const* d_in, const int* in_sizes, int n_in_args,
                              void* d_out, int out_size, void* d_ws, size_t ws_size,
                              hipStream_t stream) {
    const float* x     = (const float*)d_in[0];
    const float* w_src = (const float*)d_in[1];
    const float* w_dst = (const float*)d_in[2];
    const float* bptr  = (const float*)d_in[3];
    const int*   ei    = (const int*)d_in[4];
    const float* ew    = (const float*)d_in[5];
    const int N = in_sizes[0] / IN_CH;
    const int E = in_sizes[5];
    const int* row = ei;
    const int* col = ei + E;

    char* wsb = (char*)d_ws;
    size_t off = 0;
    auto alloc = [&](size_t bytes) -> void* {
        off = (off + 255) & ~(size_t)255;
        void* ptr = wsb + off;
        off += bytes;
        return ptr;
    };
    // 256 buckets: expected (2E)/256 = 6250 entries each, sigma ~80; big slack.
    const int bcap = E / 128 + E / 1024 + 1024;
    int2*         rc       = (int2*)alloc((size_t)E * 8);
    ull2*         adj      = (ull2*)alloc(((size_t)2 * E + 4 * N) * 16);
    uint2*        bucketA  = (uint2*)alloc((size_t)NBUCK * bcap * 8);
    float*        bucketS  = (float*)alloc((size_t)NBUCK * bcap * 4);
    unsigned int* node_max = (unsigned int*)alloc((size_t)N * 4);
    double*       denom    = (double*)alloc((size_t)N * 8);
    ull*          wsuit    = (ull*)alloc((size_t)N * 8);
    int2*         seg      = (int2*)alloc((size_t)N * 8);
    int*          cluster  = (int*)alloc((size_t)N * 4);
    int*          partner  = (int*)alloc((size_t)N * 4);
    float*        s_rep    = (float*)alloc((size_t)N * 4);
    float*        pbuf     = (float*)alloc((size_t)N * 4);
    float*        qbuf     = (float*)alloc((size_t)N * 4);
    int*          bump     = (int*)alloc(64);
    int*          btail    = (int*)alloc((size_t)NBUCK * 4);

    // Output layout: new_x[N*128] | cluster[N] | is_rep[N] | new_row[E] | new_col[E] | edge_valid[E] | edge_weight[E]
    float* out       = (float*)d_out;
    float* o_newx    = out;
    float* o_cluster = out + (size_t)N * IN_CH;
    float* o_isrep   = o_cluster + N;
    float* o_nrow    = o_isrep + N;
    float* o_ncol    = o_nrow + E;
    float* o_valid   = o_ncol + E;
    float* o_w       = o_valid + E;

    const int T = 256;
    const int TS = 1024;                    // score: 8-entry (64B bucketA) chunks at NBUCK=256
    hipLaunchKernelGGL(proj_kernel, dim3((N * 64 + T - 1) / T), dim3(T), 0, stream,
                       x, w_src, w_dst, pbuf, qbuf,
                       wsuit, cluster, partner, s_rep, bump, btail, N);
    hipLaunchKernelGGL(score_kernel, dim3((E + TS - 1) / TS), dim3(TS), 0, stream,
                       row, col, pbuf, qbuf, bptr, rc,
                       btail, bucketA, bucketS, bcap, E);
    hipLaunchKernelGGL(slot_kernel, dim3(NBUCK), dim3(1024), 0, stream,
                       bucketA, bucketS, btail, bcap, node_max, denom, bump, seg, N);
    const int bpx = 80;                     // blocks per XCD slot
    hipLaunchKernelGGL(csr_scatter_kernel, dim3(8 * bpx), dim3(T), 0, stream,
                       bucketA, bucketS, btail, bcap, node_max, denom, seg, adj, bpx);
    const int SB = ((N + 63) / 64) * 8;     // whole octets: remap covers every node
    hipLaunchKernelGGL(suitor_kernel, dim3(SB), dim3(T), 0, stream,
                       seg, adj, rc, wsuit, N);
    hipLaunchKernelGGL(extract_kernel, dim3((N + T - 1) / T), dim3(T), 0, stream,
                       rc, pbuf, qbuf, bptr, node_max, denom, wsuit,
                       cluster, partner, s_rep, N);
    const int NB1 = (N * 32 + T - 1) / T;
    const int NB2 = (E + T - 1) / T;
    hipLaunchKernelGGL(out_kernel, dim3(NB1 + NB2), dim3(T), 0, stream,
                       x, cluster, partner, s_rep, row, col, ew,
                       o_newx, o_cluster, o_isrep, o_nrow, o_ncol, o_valid, o_w, N, E, NB1);
    (void)ws_size; (void)out_size; (void)n_in_args;
}

// Round 10
// 295.382 us; speedup vs baseline: 1.2429x; 1.0018x over previous
//
#include <hip/hip_runtime.h>
#include <cmath>

#define IN_CH 128
#define NBUCK 256
#define LNMAX 196   // ceil(50048/256); node local id = node>>8
#define SIDE_BIT (1u << 20)
#define SELF_BIT (1u << 21)
// Cacheable (L1/L2) relaxed probe: ws is monotone-decreasing so stale reads are
// stale-HIGH => safe (can only cause a rejected proposal, never a wrong skip).
#define PLW(p) __hip_atomic_load((p), __ATOMIC_RELAXED, __HIP_MEMORY_SCOPE_WORKGROUP)

typedef unsigned long long ull;
typedef ull  ull2 __attribute__((ext_vector_type(2)));
typedef float f4  __attribute__((ext_vector_type(4)));

// Monotone descending key: smaller key == higher norm; ties -> smaller edge idx
// (matches stable argsort of -norm). All keys distinct. Low 32 bits = edge idx.
__device__ __forceinline__ ull make_key(float norm, int e) {
    unsigned int b = __float_as_uint(norm);
    unsigned int asc = (b & 0x80000000u) ? ~b : (b | 0x80000000u); // monotone-increasing map
    unsigned int desc = ~asc;
    return (((ull)desc) << 32) | (unsigned int)e;
}

// Norm from raw score s and source-node stats. IDENTICAL float ops to ref:
// ev=(float)exp((double)(s-m)); nv=ev/d+0.5f; 0 for non-positive; raw score
// when the source node has no positive edge.
__device__ __forceinline__ float norm_from(float s, unsigned int mb, double den) {
    if (mb != 0u) {
        if (s > 0.0f) {
            float m = __uint_as_float(mb);
            float ev = (float)exp((double)(s - m));
            float d = (float)den;
            return ev / d + 0.5f;
        }
        return 0.0f;
    }
    return s;
}

// One wave per node: p[n] = dot(x[n], w_src), q[n] = dot(x[n], w_dst), double accum.
// Per-node state init + counter zeroing folded in.
__global__ void proj_kernel(const float* __restrict__ x, const float* __restrict__ w_src,
                            const float* __restrict__ w_dst, float* __restrict__ p,
                            float* __restrict__ q,
                            ull* __restrict__ wsuit,
                            int* __restrict__ cluster, int* __restrict__ partner,
                            float* __restrict__ s_rep, int* __restrict__ bump,
                            int* __restrict__ btail, int N) {
    int gtid = blockIdx.x * blockDim.x + threadIdx.x;
    if (gtid == 0) *bump = 0;
    if (gtid < NBUCK) btail[gtid] = 0;
    if (gtid < N) {
        wsuit[gtid]    = ~0ULL;
        cluster[gtid]  = gtid;
        partner[gtid]  = gtid;
        s_rep[gtid]    = 1.0f;
    }
    int wave = gtid >> 6;
    int lane = threadIdx.x & 63;
    if (wave >= N) return;
    float2 xv = ((const float2*)(x + (size_t)wave * IN_CH))[lane];
    float2 ws = ((const float2*)w_src)[lane];
    float2 wd = ((const float2*)w_dst)[lane];
    double ap = (double)xv.x * (double)ws.x + (double)xv.y * (double)ws.y;
    double aq = (double)xv.x * (double)wd.x + (double)xv.y * (double)wd.y;
    #pragma unroll
    for (int off = 32; off > 0; off >>= 1) {
        ap += __shfl_down(ap, off);
        aq += __shfl_down(aq, off);
    }
    if (lane == 0) { p[wave] = (float)ap; q[wave] = (float)aq; }
}

// Fused: edge score + rc pack + 256-bucket build. No global atomics.
// Entries carry everything downstream kernels need:
//   bucketA[i] = { e[0:19]|side[20]|self[21],  nb[0:16]|ln[17:25] }
//   bucketS[i] = raw score float (same value for both sides of an edge)
// R10: LDS-STAGED bucket flush. Phase-1 lane-order stores hit 64 distinct
// buckets per wave (64 partial-line transactions); staging entries in LDS
// sorted by bucket and flushing in staged order makes consecutive threads
// write consecutive addresses (~8-entry contiguous runs) -> ~4-6x fewer write
// transactions on the ~32MB bucket stream. Bucket content per (bucket,block)
// is the same SET (intra-chunk order changes only); all consumers are
// order-insensitive, so output is unchanged.
__global__ void score_kernel(const int* __restrict__ row, const int* __restrict__ col,
                             const float* __restrict__ p, const float* __restrict__ q,
                             const float* __restrict__ bptr,
                             int2* __restrict__ rc, int* __restrict__ btail,
                             uint2* __restrict__ bucketA, float* __restrict__ bucketS,
                             int bcap, int E) {
    __shared__ int cnt[NBUCK];
    __shared__ int gbase[NBUCK];
    __shared__ int cincl[NBUCK];            // inclusive scan of cnt
    __shared__ unsigned int sA0[2048];
    __shared__ unsigned int sA1[2048];
    __shared__ float sS[2048];
    __shared__ unsigned short sH[2048];     // bucket id per staged entry
    int t = threadIdx.x;
    int e = blockIdx.x * blockDim.x + t;
    if (t < NBUCK) cnt[t] = 0;
    __syncthreads();
    bool inb = e < E;
    int u = 0, v = 0, l1 = -1, l2 = -1, h1 = 0, h2 = 0;
    float s = 0.0f;
    if (inb) {
        u = row[e]; v = col[e];
        rc[e] = make_int2(u, v);
        s = p[u] + q[v] + bptr[0];
        h1 = u & (NBUCK - 1); l1 = atomicAdd(&cnt[h1], 1);   // side-0 entry (always)
        if (u != v) {
            h2 = v & (NBUCK - 1); l2 = atomicAdd(&cnt[h2], 1);
        }
    }
    __syncthreads();
    if (t < NBUCK) cincl[t] = cnt[t];
    __syncthreads();
    #pragma unroll
    for (int off = 1; off < NBUCK; off <<= 1) {
        int add = (t < NBUCK && t >= off) ? cincl[t - off] : 0;
        __syncthreads();
        if (t < NBUCK) cincl[t] += add;
        __syncthreads();
    }
    if (t < NBUCK) gbase[t] = atomicAdd(&btail[t], cnt[t]);
    __syncthreads();
    int total = cincl[NBUCK - 1];
    // stage into LDS at exclusive-prefix + local idx (conflict-free slots)
    if (l1 >= 0) {
        int idx = cincl[h1] - cnt[h1] + l1;
        sA0[idx] = (unsigned int)e | ((u == v) ? SELF_BIT : 0u);
        sA1[idx] = (unsigned int)v | ((unsigned int)(u >> 8) << 17);
        sS[idx]  = s;
        sH[idx]  = (unsigned short)h1;
    }
    if (l2 >= 0) {
        int idx = cincl[h2] - cnt[h2] + l2;
        sA0[idx] = (unsigned int)e | SIDE_BIT;
        sA1[idx] = (unsigned int)u | ((unsigned int)(v >> 8) << 17);
        sS[idx]  = s;
        sH[idx]  = (unsigned short)h2;
    }
    __syncthreads();
    // coalesced flush: consecutive i within a bucket chunk -> consecutive global
    for (int i = t; i < total; i += blockDim.x) {
        int h = (int)sH[i];
        int pos = gbase[h] + (i - (cincl[h] - cnt[h]));
        size_t g = (size_t)h * bcap + pos;
        bucketA[g] = make_uint2(sA0[i], sA1[i]);
        bucketS[g] = sS[i];
    }
}

// One WG (1024 thr) per bucket; bucket b owns nodes n with (n&255)==b (<=196).
// Score comes INLINE from bucketS (no global gathers at all).
// Pass 1: node_max via LDS atomicMax over side-0 entries (incl. self).
// Pass 2: denom via LDS f64 atomicAdd; slot assignment via LDS hist; word0
// rewritten to e[0:19]|side[20]|slot[21:31]; self -> 0xFFFFFFFF.
// Pass 3: per-bucket LDS prefix-scan of 64B-padded degrees -> ONE global
// atomicAdd(bump, total) per bucket; seg[node] = base + exclusive prefix.
__global__ void slot_kernel(uint2* __restrict__ bucketA, const float* __restrict__ bucketS,
                            const int* __restrict__ btail, int bcap,
                            unsigned int* __restrict__ node_max, double* __restrict__ denom,
                            int* __restrict__ bump, int2* __restrict__ seg, int N) {
    __shared__ int hist[LNMAX];
    __shared__ unsigned int maxv[LNMAX];
    __shared__ double dden[LNMAX];
    __shared__ int scan[256];
    __shared__ int basesh;
    int b = blockIdx.x;
    int t = threadIdx.x;
    for (int i = t; i < LNMAX; i += blockDim.x) {
        hist[i] = 0; maxv[i] = 0u; dden[i] = 0.0;
    }
    __syncthreads();
    int n = btail[b];
    uint2* bkA = bucketA + (size_t)b * bcap;
    const float* bkS = bucketS + (size_t)b * bcap;
    // pass 1: per-node max of positive source-side scores
    for (int i = t; i < n; i += blockDim.x) {
        uint2 en = bkA[i];
        if (!(en.x & SIDE_BIT)) {                  // side 0 (incl. self)
            float s = bkS[i];
            if (s > 0.0f) {
                int ln = (int)((en.y >> 17) & 0x1ffu);
                atomicMax(&maxv[ln], __float_as_uint(s));
            }
        }
    }
    __syncthreads();
    // pass 2: denom accumulate + slot assign + rewrite
    for (int i = t; i < n; i += blockDim.x) {
        uint2 en = bkA[i];
        int ln = (int)((en.y >> 17) & 0x1ffu);
        if (!(en.x & SIDE_BIT)) {                  // side 0: denom contribution
            unsigned int mb = maxv[ln];
            float s = bkS[i];
            if (mb != 0u && s > 0.0f) {
                float m = __uint_as_float(mb);
                float ev = (float)exp((double)(s - m));
                atomicAdd(&dden[ln], (double)ev);
            }
        }
        if (en.x & SELF_BIT) {
            bkA[i].x = 0xFFFFFFFFu;                // self: no adjacency slot
        } else {
            int slot = atomicAdd(&hist[ln], 1);
            bkA[i].x = (en.x & 0x1fffffu) | ((unsigned int)slot << 21);
        }
    }
    __syncthreads();
    // pass 3: seg allocation via LDS inclusive scan over 256 slots (>= LNMAX)
    if (t < 256) {
        int node = (t << 8) | b;
        int d = (t < LNMAX && node < N) ? hist[t] : 0;
        scan[t] = (d + 3) & ~3;                    // 64B-padded segment size
    }
    __syncthreads();
    #pragma unroll
    for (int off = 1; off < 256; off <<= 1) {
        int add = (t < 256 && t >= off) ? scan[t - off] : 0;
        __syncthreads();
        if (t < 256) scan[t] += add;
        __syncthreads();
    }
    if (t == 255) basesh = atomicAdd(bump, scan[255]);   // ONE global RMW/bucket
    __syncthreads();
    if (t < LNMAX) {
        int node = (t << 8) | b;
        if (node < N) {
            int d  = hist[t];
            int pd = (d + 3) & ~3;
            int lo = basesh + scan[t] - pd;
            seg[node]      = make_int2(lo, lo + d);
            node_max[node] = maxv[t];
            denom[node]    = dden[t];
        }
    }
}

// Phase B: XCD-pinned CSR scatter, atomic-free (pos = seg.lo + slot).
// Key computed INLINE from entry-carried score + L2-resident node stats
// (node_max 200KB, denom 400KB, each line reused ~32x). NOT fused into slot:
// side-1 entries need REMOTE nodes' stats, which other slot blocks may not
// have written yet (inter-block race, G16); bucket re-reads are XCD-local L2
// hits anyway. bucket b -> XCD b&7 (node&7 preserved).
__global__ void csr_scatter_kernel(const uint2* __restrict__ bucketA,
                                   const float* __restrict__ bucketS,
                                   const int* __restrict__ btail, int bcap,
                                   const unsigned int* __restrict__ node_max,
                                   const double* __restrict__ denom,
                                   const int2* __restrict__ seg,
                                   ull2* __restrict__ adj, int bpx) {
    int xcd = blockIdx.x & 7;
    int sub = blockIdx.x >> 3;
    for (int bb = 0; bb < NBUCK / 8; ++bb) {
        int b = xcd + (bb << 3);
        int n = btail[b];
        const uint2* bkA = bucketA + (size_t)b * bcap;
        const float* bkS = bucketS + (size_t)b * bcap;
        for (int i = sub * blockDim.x + threadIdx.x; i < n; i += bpx * blockDim.x) {
            uint2 en = bkA[i];
            if (en.x == 0xFFFFFFFFu) continue;     // self-loop sentinel
            int e    = (int)(en.x & 0xfffffu);
            int side = (int)((en.x >> 20) & 1u);
            int slot = (int)(en.x >> 21);
            int nb   = (int)(en.y & 0x1ffffu);
            int ln   = (int)((en.y >> 17) & 0x1ffu);
            int dst  = (ln << 8) | b;
            int u    = side ? nb : dst;            // source (row) node of e
            float nv = norm_from(bkS[i], node_max[u], denom[u]);
            ull2 w; w.x = make_key(nv, e); w.y = (ull)nb;
            adj[seg[dst].x + slot] = w;
        }
    }
}

// ---- Suitor matching (Manne-Bisseling), 32-lane-group-per-node. R3 probe
// scheme (best measured): cacheable probes of ws directly (stale-high => safe
// filter), progress guaranteed by excl (a rejection proves ws[bv] <= bk;
// proposal keys strictly increase between takeovers).
// Grid MUST be whole octets of blocks (8 blocks <-> 64 nodes): ceil(N/64)*8.
__global__ void suitor_kernel(const int2* __restrict__ seg,
                              const ull2* __restrict__ adj,
                              const int2* __restrict__ rc,
                              ull* __restrict__ ws, int N) {
    int lg   = threadIdx.x >> 5;            // local group 0..7
    int b    = blockIdx.x;
    int grp  = ((((b >> 3) << 3) + lg) << 3) | (b & 7);   // node; node%8==b%8
    int lane = threadIdx.x & 31;
    if (grp >= N) return;
    int cur = grp;
    int2 lohi;
    ull excl = 0ULL;          // keys <= excl proven infeasible for cur (monotone)
    ull lk = ~0ULL;           // lane-local best candidate key
    int lv = -1;              // its neighbor
    bool reload = true;
    for (int guard = 0; guard < 1000000; ++guard) {
        if (reload) {
            lohi = seg[cur];
            excl = 0ULL;
            lk = ~0ULL; lv = -1;
            for (int i = lohi.x + lane; i < lohi.y; i += 32) {
                ull2 ent = adj[i];              // coalesced 16B
                ull k = ent.x;
                if (k < lk) {
                    int v = (int)ent.y;
                    if (k < PLW(&ws[v])) { lk = k; lv = v; }  // cached probe
                }
            }
            reload = false;
        } else if (lk != ~0ULL && lk <= excl) {
            // this lane owned the rejected key: recompute from its entries
            lk = ~0ULL; lv = -1;
            for (int i = lohi.x + lane; i < lohi.y; i += 32) {
                ull2 ent = adj[i];              // L1/L2-hot re-read, 1-2 entries
                ull k = ent.x;
                if (k > excl && k < lk) {
                    int v = (int)ent.y;
                    if (k < PLW(&ws[v])) { lk = k; lv = v; }
                }
            }
        }
        // group-wide butterfly min-reduce with payload (width 32)
        ull bk = lk; int bv = lv;
        #pragma unroll
        for (int off = 16; off > 0; off >>= 1) {
            ull ok = __shfl_xor(bk, off, 32);
            int ov = __shfl_xor(bv, off, 32);
            if (ok < bk) { bk = ok; bv = ov; }
        }
        if (bk == ~0ULL) break;             // no feasible proposal: cur stays unmatched
        ull old;
        if (lane == 0) old = atomicMin(&ws[bv], bk);
        old = __shfl(old, 0, 32);
        if (old <= bk) {
            excl = bk;                      // proven infeasible; next proposal key > bk
            continue;
        }
        // accepted; take over the displaced proposer (atomicMin hands each
        // displaced value to exactly one group)
        if (old == ~0ULL) break;
        int e = (int)(old & 0xffffffffu);
        int2 pr = rc[e];                    // same address across group -> broadcast
        cur = pr.x ^ pr.y ^ bv;             // displaced proposer = other endpoint of e
        reload = true;
    }
}

// Node-centric extract: each node's standing proposal names its edge; matched
// iff mutual (ws[a]==ws[b]==k). The a-side thread writes (once per pair).
// s_rep recomputed inline: s = p[a]+q[b]+bias (bit-identical to score_kernel's
// expression) + L2-resident stats.
__global__ void extract_kernel(const int2* __restrict__ rc,
                               const float* __restrict__ p, const float* __restrict__ q,
                               const float* __restrict__ bptr,
                               const unsigned int* __restrict__ node_max,
                               const double* __restrict__ denom,
                               const ull* __restrict__ ws,
                               int* __restrict__ cluster, int* __restrict__ partner,
                               float* __restrict__ s_rep, int N) {
    int w = blockIdx.x * blockDim.x + threadIdx.x;
    if (w >= N) return;
    ull k = ws[w];
    if (k == ~0ULL) return;
    int e = (int)(k & 0xffffffffu);
    int2 pr = rc[e];                        // w is an endpoint of e
    int a = pr.x, b = pr.y;
    if (w != a) return;                     // b-side duplicate: skip
    if (ws[b] == k) {                       // mutual => matched (ws[a]==k by construction)
        cluster[b] = a;                     // b merged into rep a (ref: cluster[c_s]=r_s)
        partner[a] = b;
        float s = p[a] + q[b] + bptr[0];    // same float ops as score_kernel
        s_rep[a] = norm_from(s, node_max[a], denom[a]);
    }
}

// Fused epilogue: blocks [0, NB1) do new_x/cluster/is_rep; blocks [NB1, ..) do
// edges. nt ONLY on the fully-coalesced f4 newx stream.
__global__ void out_kernel(const float* __restrict__ x, const int* __restrict__ cluster,
                           const int* __restrict__ partner, const float* __restrict__ s_rep,
                           const int* __restrict__ row, const int* __restrict__ col,
                           const float* __restrict__ w,
                           float* __restrict__ out_newx, float* __restrict__ out_cluster,
                           float* __restrict__ out_isrep, float* __restrict__ out_nrow,
                           float* __restrict__ out_ncol, float* __restrict__ out_valid,
                           float* __restrict__ out_w, int N, int E, int NB1) {
    if ((int)blockIdx.x < NB1) {
        int t = blockIdx.x * blockDim.x + threadIdx.x;
        if (t >= N * (IN_CH / 4)) return;
        int n = t >> 5;            // IN_CH/4 == 32 float4 per node
        int c = (t & 31) * 4;
        int cl = cluster[n];
        if ((t & 31) == 0) {
            out_cluster[n] = (float)cl;
            out_isrep[n]   = (cl == n) ? 1.0f : 0.0f;
        }
        f4 o;
        int v = partner[n];
        if (cl != n) {
            o = (f4)0.0f;                                     // merged-away node row
        } else if (v != n) {
            float s = s_rep[n];
            f4 xu = *(const f4*)(x + (size_t)n * IN_CH + c);
            f4 xv = *(const f4*)(x + (size_t)v * IN_CH + c);
            o = (xu + xv) * s + xv;
        } else {
            o = *(const f4*)(x + (size_t)n * IN_CH + c);      // untouched node
        }
        __builtin_nontemporal_store(o, (f4*)out_newx + t);
    } else {
        int e = (blockIdx.x - NB1) * blockDim.x + threadIdx.x;
        if (e >= E) return;
        int nr = cluster[row[e]];
        int nc = cluster[col[e]];
        out_nrow[e]  = (float)nr;
        out_ncol[e]  = (float)nc;
        out_valid[e] = (nr != nc) ? 1.0f : 0.0f;
        out_w[e]     = w[e];
    }
}

extern "C" void kernel_launch(void* const* d_in, const int* in_sizes, int n_in_args,
                              void* d_out, int out_size, void* d_ws, size_t ws_size,
                              hipStream_t stream) {
    const float* x     = (const float*)d_in[0];
    const float* w_src = (const float*)d_in[1];
    const float* w_dst = (const float*)d_in[2];
    const float* bptr  = (const float*)d_in[3];
    const int*   ei    = (const int*)d_in[4];
    const float* ew    = (const float*)d_in[5];
    const int N = in_sizes[0] / IN_CH;
    const int E = in_sizes[5];
    const int* row = ei;
    const int* col = ei + E;

    char* wsb = (char*)d_ws;
    size_t off = 0;
    auto alloc = [&](size_t bytes) -> void* {
        off = (off + 255) & ~(size_t)255;
        void* ptr = wsb + off;
        off += bytes;
        return ptr;
    };
    // 256 buckets: expected (2E)/256 = 6250 entries each, sigma ~80; big slack.
    const int bcap = E / 128 + E / 1024 + 1024;
    int2*         rc       = (int2*)alloc((size_t)E * 8);
    ull2*         adj      = (ull2*)alloc(((size_t)2 * E + 4 * N) * 16);
    uint2*        bucketA  = (uint2*)alloc((size_t)NBUCK * bcap * 8);
    float*        bucketS  = (float*)alloc((size_t)NBUCK * bcap * 4);
    unsigned int* node_max = (unsigned int*)alloc((size_t)N * 4);
    double*       denom    = (double*)alloc((size_t)N * 8);
    ull*          wsuit    = (ull*)alloc((size_t)N * 8);
    int2*         seg      = (int2*)alloc((size_t)N * 8);
    int*          cluster  = (int*)alloc((size_t)N * 4);
    int*          partner  = (int*)alloc((size_t)N * 4);
    float*        s_rep    = (float*)alloc((size_t)N * 4);
    float*        pbuf     = (float*)alloc((size_t)N * 4);
    float*        qbuf     = (float*)alloc((size_t)N * 4);
    int*          bump     = (int*)alloc(64);
    int*          btail    = (int*)alloc((size_t)NBUCK * 4);

    // Output layout: new_x[N*128] | cluster[N] | is_rep[N] | new_row[E] | new_col[E] | edge_valid[E] | edge_weight[E]
    float* out       = (float*)d_out;
    float* o_newx    = out;
    float* o_cluster = out + (size_t)N * IN_CH;
    float* o_isrep   = o_cluster + N;
    float* o_nrow    = o_isrep + N;
    float* o_ncol    = o_nrow + E;
    float* o_valid   = o_ncol + E;
    float* o_w       = o_valid + E;

    const int T = 256;
    const int TS = 1024;                    // score: 1024 edges/block, LDS-staged flush
    hipLaunchKernelGGL(proj_kernel, dim3((N * 64 + T - 1) / T), dim3(T), 0, stream,
                       x, w_src, w_dst, pbuf, qbuf,
                       wsuit, cluster, partner, s_rep, bump, btail, N);
    hipLaunchKernelGGL(score_kernel, dim3((E + TS - 1) / TS), dim3(TS), 0, stream,
                       row, col, pbuf, qbuf, bptr, rc,
                       btail, bucketA, bucketS, bcap, E);
    hipLaunchKernelGGL(slot_kernel, dim3(NBUCK), dim3(1024), 0, stream,
                       bucketA, bucketS, btail, bcap, node_max, denom, bump, seg, N);
    const int bpx = 80;                     // blocks per XCD slot
    hipLaunchKernelGGL(csr_scatter_kernel, dim3(8 * bpx), dim3(T), 0, stream,
                       bucketA, bucketS, btail, bcap, node_max, denom, seg, adj, bpx);
    const int SB = ((N + 63) / 64) * 8;     // whole octets: remap covers every node
    hipLaunchKernelGGL(suitor_kernel, dim3(SB), dim3(T), 0, stream,
                       seg, adj, rc, wsuit, N);
    hipLaunchKernelGGL(extract_kernel, dim3((N + T - 1) / T), dim3(T), 0, stream,
                       rc, pbuf, qbuf, bptr, node_max, denom, wsuit,
                       cluster, partner, s_rep, N);
    const int NB1 = (N * 32 + T - 1) / T;
    const int NB2 = (E + T - 1) / T;
    hipLaunchKernelGGL(out_kernel, dim3(NB1 + NB2), dim3(T), 0, stream,
                       x, cluster, partner, s_rep, row, col, ew,
                       o_newx, o_cluster, o_isrep, o_nrow, o_ncol, o_valid, o_w, N, E, NB1);
    (void)ws_size; (void)out_size; (void)n_in_args;
}

// Round 12
// 284.090 us; speedup vs baseline: 1.2923x; 1.0397x over previous
//
#include <hip/hip_runtime.h>
#include <cmath>

#define IN_CH 128
#define NBUCK 256
#define LNMAX 196   // ceil(50048/256); node local id = node>>8
#define SIDE_BIT (1u << 20)
#define SELF_BIT (1u << 21)
// Cacheable (L1/L2) relaxed probe: ws is monotone-decreasing so stale reads are
// stale-HIGH => safe (can only cause a rejected proposal, never a wrong skip).
#define PLW(p) __hip_atomic_load((p), __ATOMIC_RELAXED, __HIP_MEMORY_SCOPE_WORKGROUP)

typedef unsigned long long ull;
typedef ull  ull2 __attribute__((ext_vector_type(2)));
typedef float f4  __attribute__((ext_vector_type(4)));

// Monotone descending key: smaller key == higher norm; ties -> smaller edge idx
// (matches stable argsort of -norm). All keys distinct. Low 32 bits = edge idx.
__device__ __forceinline__ ull make_key(float norm, int e) {
    unsigned int b = __float_as_uint(norm);
    unsigned int asc = (b & 0x80000000u) ? ~b : (b | 0x80000000u); // monotone-increasing map
    unsigned int desc = ~asc;
    return (((ull)desc) << 32) | (unsigned int)e;
}

// Norm from raw score s and source-node stats. IDENTICAL float ops to ref:
// ev=(float)exp((double)(s-m)); nv=ev/d+0.5f; 0 for non-positive; raw score
// when the source node has no positive edge.
__device__ __forceinline__ float norm_from(float s, unsigned int mb, double den) {
    if (mb != 0u) {
        if (s > 0.0f) {
            float m = __uint_as_float(mb);
            float ev = (float)exp((double)(s - m));
            float d = (float)den;
            return ev / d + 0.5f;
        }
        return 0.0f;
    }
    return s;
}

// One wave per node: p[n] = dot(x[n], w_src), q[n] = dot(x[n], w_dst), double accum.
// Per-node state init + counter zeroing folded in.
__global__ void proj_kernel(const float* __restrict__ x, const float* __restrict__ w_src,
                            const float* __restrict__ w_dst, float* __restrict__ p,
                            float* __restrict__ q,
                            ull* __restrict__ wsuit,
                            int* __restrict__ cluster, int* __restrict__ partner,
                            float* __restrict__ s_rep,
                            int* __restrict__ btail, int N) {
    int gtid = blockIdx.x * blockDim.x + threadIdx.x;
    if (gtid < NBUCK) btail[gtid] = 0;
    if (gtid < N) {
        wsuit[gtid]    = ~0ULL;
        cluster[gtid]  = gtid;
        partner[gtid]  = gtid;
        s_rep[gtid]    = 1.0f;
    }
    int wave = gtid >> 6;
    int lane = threadIdx.x & 63;
    if (wave >= N) return;
    float2 xv = ((const float2*)(x + (size_t)wave * IN_CH))[lane];
    float2 ws = ((const float2*)w_src)[lane];
    float2 wd = ((const float2*)w_dst)[lane];
    double ap = (double)xv.x * (double)ws.x + (double)xv.y * (double)ws.y;
    double aq = (double)xv.x * (double)wd.x + (double)xv.y * (double)wd.y;
    #pragma unroll
    for (int off = 32; off > 0; off >>= 1) {
        ap += __shfl_down(ap, off);
        aq += __shfl_down(aq, off);
    }
    if (lane == 0) { p[wave] = (float)ap; q[wave] = (float)aq; }
}

// Fused: edge score + rc pack + 256-bucket build (LDS-staged flush, R10).
// Entries carry everything downstream kernels need:
//   bucketA[i] = { e[0:19]|side[20]|self[21],  nb[0:16]|ln[17:25] }
//   bucketS[i] = raw score float (same value for both sides of an edge)
// Self-loops (u==v): one side-0 entry with self=1 (contributes to node_max/
// denom, never enters adjacency).
__global__ void score_kernel(const int* __restrict__ row, const int* __restrict__ col,
                             const float* __restrict__ p, const float* __restrict__ q,
                             const float* __restrict__ bptr,
                             int2* __restrict__ rc, int* __restrict__ btail,
                             uint2* __restrict__ bucketA, float* __restrict__ bucketS,
                             int bcap, int E) {
    __shared__ int cnt[NBUCK];
    __shared__ int gbase[NBUCK];
    __shared__ int cincl[NBUCK];            // inclusive scan of cnt
    __shared__ unsigned int sA0[2048];
    __shared__ unsigned int sA1[2048];
    __shared__ float sS[2048];
    __shared__ unsigned short sH[2048];     // bucket id per staged entry
    int t = threadIdx.x;
    int e = blockIdx.x * blockDim.x + t;
    if (t < NBUCK) cnt[t] = 0;
    __syncthreads();
    bool inb = e < E;
    int u = 0, v = 0, l1 = -1, l2 = -1, h1 = 0, h2 = 0;
    float s = 0.0f;
    if (inb) {
        u = row[e]; v = col[e];
        rc[e] = make_int2(u, v);
        s = p[u] + q[v] + bptr[0];
        h1 = u & (NBUCK - 1); l1 = atomicAdd(&cnt[h1], 1);   // side-0 entry (always)
        if (u != v) {
            h2 = v & (NBUCK - 1); l2 = atomicAdd(&cnt[h2], 1);
        }
    }
    __syncthreads();
    if (t < NBUCK) cincl[t] = cnt[t];
    __syncthreads();
    #pragma unroll
    for (int off = 1; off < NBUCK; off <<= 1) {
        int add = (t < NBUCK && t >= off) ? cincl[t - off] : 0;
        __syncthreads();
        if (t < NBUCK) cincl[t] += add;
        __syncthreads();
    }
    if (t < NBUCK) gbase[t] = atomicAdd(&btail[t], cnt[t]);
    __syncthreads();
    int total = cincl[NBUCK - 1];
    // stage into LDS at exclusive-prefix + local idx (conflict-free slots)
    if (l1 >= 0) {
        int idx = cincl[h1] - cnt[h1] + l1;
        sA0[idx] = (unsigned int)e | ((u == v) ? SELF_BIT : 0u);
        sA1[idx] = (unsigned int)v | ((unsigned int)(u >> 8) << 17);
        sS[idx]  = s;
        sH[idx]  = (unsigned short)h1;
    }
    if (l2 >= 0) {
        int idx = cincl[h2] - cnt[h2] + l2;
        sA0[idx] = (unsigned int)e | SIDE_BIT;
        sA1[idx] = (unsigned int)u | ((unsigned int)(v >> 8) << 17);
        sS[idx]  = s;
        sH[idx]  = (unsigned short)h2;
    }
    __syncthreads();
    // coalesced flush: consecutive i within a bucket chunk -> consecutive global
    for (int i = t; i < total; i += blockDim.x) {
        int h = (int)sH[i];
        int pos = gbase[h] + (i - (cincl[h] - cnt[h]));
        size_t g = (size_t)h * bcap + pos;
        bucketA[g] = make_uint2(sA0[i], sA1[i]);
        bucketS[g] = sS[i];
    }
}

// One WG (1024 thr) per bucket; bucket b owns nodes n with (n&255)==b (<=196).
// R11/R12: slot PERMUTES entries into node-major order, writing the packed
// form DIRECTLY INTO adj (in-place pre-key form) -- no perm buffers, keeping
// workspace under the proven ~61MB (R11's +30MB permA/permS overflowed the
// workspace -> GPU fault -> container death).
//   adj[pos] (pre-key) = { meta<<32 | score_bits,  nb }
//   meta = e[0:19]|side[20]|ln[21:28]
// Global bump allocator gone: bucket b's segments live in [b*bcap,(b+1)*bcap);
// seg[node] = b*bcap + exclusive-prefix. Adjacency per node is the same SET
// as the R10 pipeline (order differs); all consumers are order-insensitive.
// Pass 1: node_max (side-0 incl self) + per-node adjacency count (non-self).
// Pass 2: LDS scan of counts -> per-node exclusive offsets (cursor init).
// Pass 3: denom accumulate (side-0) + packed placement into adj (scattered
//         only within the bucket's ~112KB region -> L2-local).
__global__ void slot_kernel(const uint2* __restrict__ bucketA,
                            const float* __restrict__ bucketS,
                            const int* __restrict__ btail, int bcap,
                            ull2* __restrict__ adj, int* __restrict__ bcount,
                            unsigned int* __restrict__ node_max, double* __restrict__ denom,
                            int2* __restrict__ seg, int N) {
    __shared__ int hist[LNMAX];
    __shared__ unsigned int maxv[LNMAX];
    __shared__ double dden[LNMAX];
    __shared__ int cursor[LNMAX];
    __shared__ int scan[256];
    __shared__ int selfcnt;
    int b = blockIdx.x;
    int t = threadIdx.x;
    for (int i = t; i < LNMAX; i += blockDim.x) {
        hist[i] = 0; maxv[i] = 0u; dden[i] = 0.0;
    }
    if (t == 0) selfcnt = 0;
    __syncthreads();
    int n = btail[b];
    const uint2* bkA = bucketA + (size_t)b * bcap;
    const float* bkS = bucketS + (size_t)b * bcap;
    ull2* ad = adj + (size_t)b * bcap;
    // pass 1: per-node max of positive source-side scores + adjacency counts
    for (int i = t; i < n; i += blockDim.x) {
        uint2 en = bkA[i];
        int ln = (int)((en.y >> 17) & 0x1ffu);
        if (!(en.x & SIDE_BIT)) {                  // side 0 (incl. self)
            float s = bkS[i];
            if (s > 0.0f) atomicMax(&maxv[ln], __float_as_uint(s));
        }
        if (en.x & SELF_BIT) atomicAdd(&selfcnt, 1);
        else                 atomicAdd(&hist[ln], 1);
    }
    __syncthreads();
    // pass 2: inclusive scan of counts -> per-node offsets
    if (t < 256) scan[t] = (t < LNMAX) ? hist[t] : 0;
    __syncthreads();
    #pragma unroll
    for (int off = 1; off < 256; off <<= 1) {
        int add = (t < 256 && t >= off) ? scan[t - off] : 0;
        __syncthreads();
        if (t < 256) scan[t] += add;
        __syncthreads();
    }
    if (t < LNMAX) cursor[t] = scan[t] - hist[t];  // exclusive prefix
    __syncthreads();
    // pass 3: denom accumulate + packed node-major placement into adj
    for (int i = t; i < n; i += blockDim.x) {
        uint2 en = bkA[i];
        int ln = (int)((en.y >> 17) & 0x1ffu);
        if (!(en.x & SIDE_BIT)) {                  // side 0: denom contribution
            unsigned int mb = maxv[ln];
            float s = bkS[i];
            if (mb != 0u && s > 0.0f) {
                float m = __uint_as_float(mb);
                float ev = (float)exp((double)(s - m));
                atomicAdd(&dden[ln], (double)ev);
            }
        }
        if (!(en.x & SELF_BIT)) {
            int pos = atomicAdd(&cursor[ln], 1);
            unsigned int meta = (en.x & 0x1fffffu) | ((unsigned int)ln << 21);
            ull2 w;
            w.x = ((ull)meta << 32) | (ull)__float_as_uint(bkS[i]);
            w.y = (ull)(en.y & 0x1ffffu);          // nb
            ad[pos] = w;
        }
    }
    __syncthreads();
    if (t == 0) bcount[b] = n - selfcnt;
    if (t < LNMAX) {
        int node = (t << 8) | b;
        if (node < N) {
            int d  = hist[t];
            int lo = b * bcap + (scan[t] - d);     // absolute adj index
            seg[node]      = make_int2(lo, lo + d);
            node_max[node] = maxv[t];
            denom[node]    = dden[t];
        }
    }
}

// Phase B (R12): pure STREAMING in-place key fill. Reads adj's packed pre-key
// form coalesced, computes the key from the entry-carried score + L2-resident
// node stats (node_max 200KB, denom 400KB, read-only, reuse ~32x), overwrites
// adj[i] = (key, nb) coalesced IN PLACE. No seg gathers, no scattered writes,
// no extra buffers. Key arithmetic identical on both sides of an edge -> same
// key -> extract mutuality preserved; output unchanged. bucket b -> XCD b&7:
// adj region stays dirty-local to the XCD whose suitor groups read it.
__global__ void key_fill_kernel(ull2* __restrict__ adj,
                                const int* __restrict__ bcount, int bcap,
                                const unsigned int* __restrict__ node_max,
                                const double* __restrict__ denom, int bpx) {
    int xcd = blockIdx.x & 7;
    int sub = blockIdx.x >> 3;
    for (int bb = 0; bb < NBUCK / 8; ++bb) {
        int b = xcd + (bb << 3);
        int n = bcount[b];
        ull2* ad = adj + (size_t)b * bcap;
        for (int i = sub * blockDim.x + threadIdx.x; i < n; i += bpx * blockDim.x) {
            ull2 en = ad[i];
            unsigned int meta = (unsigned int)(en.x >> 32);
            float s  = __uint_as_float((unsigned int)(en.x & 0xffffffffu));
            int e    = (int)(meta & 0xfffffu);
            int side = (int)((meta >> 20) & 1u);
            int ln   = (int)(meta >> 21);
            int nb   = (int)en.y;
            int u    = side ? nb : ((ln << 8) | b);   // source (row) node of e
            float nv = norm_from(s, node_max[u], denom[u]);
            ull2 w; w.x = make_key(nv, e); w.y = (ull)nb;
            ad[i] = w;
        }
    }
}

// ---- Suitor matching (Manne-Bisseling), 32-lane-group-per-node. R3 probe
// scheme (best measured): cacheable probes of ws directly (stale-high => safe
// filter), progress guaranteed by excl (a rejection proves ws[bv] <= bk;
// proposal keys strictly increase between takeovers). UNCHANGED since R7.
// Grid MUST be whole octets of blocks (8 blocks <-> 64 nodes): ceil(N/64)*8.
__global__ void suitor_kernel(const int2* __restrict__ seg,
                              const ull2* __restrict__ adj,
                              const int2* __restrict__ rc,
                              ull* __restrict__ ws, int N) {
    int lg   = threadIdx.x >> 5;            // local group 0..7
    int b    = blockIdx.x;
    int grp  = ((((b >> 3) << 3) + lg) << 3) | (b & 7);   // node; node%8==b%8
    int lane = threadIdx.x & 31;
    if (grp >= N) return;
    int cur = grp;
    int2 lohi;
    ull excl = 0ULL;          // keys <= excl proven infeasible for cur (monotone)
    ull lk = ~0ULL;           // lane-local best candidate key
    int lv = -1;              // its neighbor
    bool reload = true;
    for (int guard = 0; guard < 1000000; ++guard) {
        if (reload) {
            lohi = seg[cur];
            excl = 0ULL;
            lk = ~0ULL; lv = -1;
            for (int i = lohi.x + lane; i < lohi.y; i += 32) {
                ull2 ent = adj[i];              // coalesced 16B
                ull k = ent.x;
                if (k < lk) {
                    int v = (int)ent.y;
                    if (k < PLW(&ws[v])) { lk = k; lv = v; }  // cached probe
                }
            }
            reload = false;
        } else if (lk != ~0ULL && lk <= excl) {
            // this lane owned the rejected key: recompute from its entries
            lk = ~0ULL; lv = -1;
            for (int i = lohi.x + lane; i < lohi.y; i += 32) {
                ull2 ent = adj[i];              // L1/L2-hot re-read, 1-2 entries
                ull k = ent.x;
                if (k > excl && k < lk) {
                    int v = (int)ent.y;
                    if (k < PLW(&ws[v])) { lk = k; lv = v; }
                }
            }
        }
        // group-wide butterfly min-reduce with payload (width 32)
        ull bk = lk; int bv = lv;
        #pragma unroll
        for (int off = 16; off > 0; off >>= 1) {
            ull ok = __shfl_xor(bk, off, 32);
            int ov = __shfl_xor(bv, off, 32);
            if (ok < bk) { bk = ok; bv = ov; }
        }
        if (bk == ~0ULL) break;             // no feasible proposal: cur stays unmatched
        ull old;
        if (lane == 0) old = atomicMin(&ws[bv], bk);
        old = __shfl(old, 0, 32);
        if (old <= bk) {
            excl = bk;                      // proven infeasible; next proposal key > bk
            continue;
        }
        // accepted; take over the displaced proposer (atomicMin hands each
        // displaced value to exactly one group)
        if (old == ~0ULL) break;
        int e = (int)(old & 0xffffffffu);
        int2 pr = rc[e];                    // same address across group -> broadcast
        cur = pr.x ^ pr.y ^ bv;             // displaced proposer = other endpoint of e
        reload = true;
    }
}

// Node-centric extract: each node's standing proposal names its edge; matched
// iff mutual (ws[a]==ws[b]==k). The a-side thread writes (once per pair).
// s_rep recomputed inline: s = p[a]+q[b]+bias (bit-identical to score_kernel's
// expression) + L2-resident stats.
__global__ void extract_kernel(const int2* __restrict__ rc,
                               const float* __restrict__ p, const float* __restrict__ q,
                               const float* __restrict__ bptr,
                               const unsigned int* __restrict__ node_max,
                               const double* __restrict__ denom,
                               const ull* __restrict__ ws,
                               int* __restrict__ cluster, int* __restrict__ partner,
                               float* __restrict__ s_rep, int N) {
    int w = blockIdx.x * blockDim.x + threadIdx.x;
    if (w >= N) return;
    ull k = ws[w];
    if (k == ~0ULL) return;
    int e = (int)(k & 0xffffffffu);
    int2 pr = rc[e];                        // w is an endpoint of e
    int a = pr.x, b = pr.y;
    if (w != a) return;                     // b-side duplicate: skip
    if (ws[b] == k) {                       // mutual => matched (ws[a]==k by construction)
        cluster[b] = a;                     // b merged into rep a (ref: cluster[c_s]=r_s)
        partner[a] = b;
        float s = p[a] + q[b] + bptr[0];    // same float ops as score_kernel
        s_rep[a] = norm_from(s, node_max[a], denom[a]);
    }
}

// Fused epilogue: blocks [0, NB1) do new_x/cluster/is_rep; blocks [NB1, ..) do
// edges. nt ONLY on the fully-coalesced f4 newx stream.
__global__ void out_kernel(const float* __restrict__ x, const int* __restrict__ cluster,
                           const int* __restrict__ partner, const float* __restrict__ s_rep,
                           const int* __restrict__ row, const int* __restrict__ col,
                           const float* __restrict__ w,
                           float* __restrict__ out_newx, float* __restrict__ out_cluster,
                           float* __restrict__ out_isrep, float* __restrict__ out_nrow,
                           float* __restrict__ out_ncol, float* __restrict__ out_valid,
                           float* __restrict__ out_w, int N, int E, int NB1) {
    if ((int)blockIdx.x < NB1) {
        int t = blockIdx.x * blockDim.x + threadIdx.x;
        if (t >= N * (IN_CH / 4)) return;
        int n = t >> 5;            // IN_CH/4 == 32 float4 per node
        int c = (t & 31) * 4;
        int cl = cluster[n];
        if ((t & 31) == 0) {
            out_cluster[n] = (float)cl;
            out_isrep[n]   = (cl == n) ? 1.0f : 0.0f;
        }
        f4 o;
        int v = partner[n];
        if (cl != n) {
            o = (f4)0.0f;                                     // merged-away node row
        } else if (v != n) {
            float s = s_rep[n];
            f4 xu = *(const f4*)(x + (size_t)n * IN_CH + c);
            f4 xv = *(const f4*)(x + (size_t)v * IN_CH + c);
            o = (xu + xv) * s + xv;
        } else {
            o = *(const f4*)(x + (size_t)n * IN_CH + c);      // untouched node
        }
        __builtin_nontemporal_store(o, (f4*)out_newx + t);
    } else {
        int e = (blockIdx.x - NB1) * blockDim.x + threadIdx.x;
        if (e >= E) return;
        int nr = cluster[row[e]];
        int nc = cluster[col[e]];
        out_nrow[e]  = (float)nr;
        out_ncol[e]  = (float)nc;
        out_valid[e] = (nr != nc) ? 1.0f : 0.0f;
        out_w[e]     = w[e];
    }
}

extern "C" void kernel_launch(void* const* d_in, const int* in_sizes, int n_in_args,
                              void* d_out, int out_size, void* d_ws, size_t ws_size,
                              hipStream_t stream) {
    const float* x     = (const float*)d_in[0];
    const float* w_src = (const float*)d_in[1];
    const float* w_dst = (const float*)d_in[2];
    const float* bptr  = (const float*)d_in[3];
    const int*   ei    = (const int*)d_in[4];
    const float* ew    = (const float*)d_in[5];
    const int N = in_sizes[0] / IN_CH;
    const int E = in_sizes[5];
    const int* row = ei;
    const int* col = ei + E;

    char* wsb = (char*)d_ws;
    size_t off = 0;
    auto alloc = [&](size_t bytes) -> void* {
        off = (off + 255) & ~(size_t)255;
        void* ptr = wsb + off;
        off += bytes;
        return ptr;
    };
    // 256 buckets: mean (2E)/256 = 6250 entries, sigma ~79; +768 ≈ +9.7 sigma
    // slack, 4-aligned. Workspace total ~58.5MB (< proven-safe ~61MB; R11's
    // ~91MB was the suspected container-killer).
    const int bcap = ((E / 128 + 768 + 3) / 4) * 4;
    int2*         rc       = (int2*)alloc((size_t)E * 8);
    ull2*         adj      = (ull2*)alloc((size_t)NBUCK * bcap * 16);
    uint2*        bucketA  = (uint2*)alloc((size_t)NBUCK * bcap * 8);
    float*        bucketS  = (float*)alloc((size_t)NBUCK * bcap * 4);
    unsigned int* node_max = (unsigned int*)alloc((size_t)N * 4);
    double*       denom    = (double*)alloc((size_t)N * 8);
    ull*          wsuit    = (ull*)alloc((size_t)N * 8);
    int2*         seg      = (int2*)alloc((size_t)N * 8);
    int*          cluster  = (int*)alloc((size_t)N * 4);
    int*          partner  = (int*)alloc((size_t)N * 4);
    float*        s_rep    = (float*)alloc((size_t)N * 4);
    float*        pbuf     = (float*)alloc((size_t)N * 4);
    float*        qbuf     = (float*)alloc((size_t)N * 4);
    int*          btail    = (int*)alloc((size_t)NBUCK * 4);
    int*          bcount   = (int*)alloc((size_t)NBUCK * 4);

    // Output layout: new_x[N*128] | cluster[N] | is_rep[N] | new_row[E] | new_col[E] | edge_valid[E] | edge_weight[E]
    float* out       = (float*)d_out;
    float* o_newx    = out;
    float* o_cluster = out + (size_t)N * IN_CH;
    float* o_isrep   = o_cluster + N;
    float* o_nrow    = o_isrep + N;
    float* o_ncol    = o_nrow + E;
    float* o_valid   = o_ncol + E;
    float* o_w       = o_valid + E;

    const int T = 256;
    const int TS = 1024;                    // score: 1024 edges/block, LDS-staged flush
    hipLaunchKernelGGL(proj_kernel, dim3((N * 64 + T - 1) / T), dim3(T), 0, stream,
                       x, w_src, w_dst, pbuf, qbuf,
                       wsuit, cluster, partner, s_rep, btail, N);
    hipLaunchKernelGGL(score_kernel, dim3((E + TS - 1) / TS), dim3(TS), 0, stream,
                       row, col, pbuf, qbuf, bptr, rc,
                       btail, bucketA, bucketS, bcap, E);
    hipLaunchKernelGGL(slot_kernel, dim3(NBUCK), dim3(1024), 0, stream,
                       bucketA, bucketS, btail, bcap, adj, bcount,
                       node_max, denom, seg, N);
    const int bpx = 80;                     // blocks per XCD slot
    hipLaunchKernelGGL(key_fill_kernel, dim3(8 * bpx), dim3(T), 0, stream,
                       adj, bcount, bcap, node_max, denom, bpx);
    const int SB = ((N + 63) / 64) * 8;     // whole octets: remap covers every node
    hipLaunchKernelGGL(suitor_kernel, dim3(SB), dim3(T), 0, stream,
                       seg, adj, rc, wsuit, N);
    hipLaunchKernelGGL(extract_kernel, dim3((N + T - 1) / T), dim3(T), 0, stream,
                       rc, pbuf, qbuf, bptr, node_max, denom, wsuit,
                       cluster, partner, s_rep, N);
    const int NB1 = (N * 32 + T - 1) / T;
    const int NB2 = (E + T - 1) / T;
    hipLaunchKernelGGL(out_kernel, dim3(NB1 + NB2), dim3(T), 0, stream,
                       x, cluster, partner, s_rep, row, col, ew,
                       o_newx, o_cluster, o_isrep, o_nrow, o_ncol, o_valid, o_w, N, E, NB1);
    (void)ws_size; (void)out_size; (void)n_in_args;
}